// Round 3
// baseline (748.658 us; speedup 1.0000x reference)
//
#include <hip/hip_runtime.h>
#include <hip/hip_bf16.h>
#include <stdint.h>

typedef unsigned int uint32;
typedef unsigned short ushort16;

typedef __attribute__((ext_vector_type(8))) short short8;
typedef __attribute__((ext_vector_type(4))) float f32x4;

#define N_NODES 50000
#define N_EDGES 800000
#define FD      128
#define NGRAPH  64
#define MTILES  3125   // N_NODES / 16 exactly

__device__ __forceinline__ float bf2f(ushort16 u){
  union { uint32 i; float f; } v; v.i = ((uint32)u) << 16; return v.f;
}
__device__ __forceinline__ float bf2f_lo(uint32 w){ union{uint32 i;float f;}v; v.i = w << 16; return v.f; }
__device__ __forceinline__ float bf2f_hi(uint32 w){ union{uint32 i;float f;}v; v.i = w & 0xffff0000u; return v.f; }
__device__ __forceinline__ ushort16 f2bf(float f){
  uint32 u = __float_as_uint(f);
  u += 0x7fffu + ((u >> 16) & 1u);   // round-to-nearest-even
  return (ushort16)(u >> 16);
}

// flags[0] = 1 iff float inputs are f32 (else bf16); flags[1] = 1 iff indices are int64
__device__ __forceinline__ int ld_idx(const void* p, uint32 is64, size_t i){
  return is64 ? (int)((const long long*)p)[i] : ((const int*)p)[i];
}
__device__ __forceinline__ float ld_f(const void* p, uint32 isf32, int i){
  return isf32 ? ((const float*)p)[i] : bf2f(((const ushort16*)p)[i]);
}

// ---------------- dtype detection (device-side, 1 wave) ----------------

__global__ void detect_kernel(const uint32* __restrict__ xw, const uint32* __restrict__ eiw,
                              uint32* __restrict__ flags)
{
  int t = threadIdx.x;                       // 64 lanes
  uint32 w = xw[t];
  uint32 e8 = (w >> 7) & 0xFFu;              // exponent field of the LOW bf16 half
  bool bf_like = (e8 >= 0x70u && e8 <= 0x82u); // |v| in [2^-15, 8] — N(0,1) bf16 ~always
  unsigned long long m = __ballot(bf_like);  // bf16 data -> ~64 hits; f32 mantissa noise -> ~5
  uint32 hi = (t < 8) ? eiw[2*t + 1] : 1u;   // odd words: int64 high halves are 0
  unsigned long long z = __ballot(hi == 0u);
  if (t == 0){
    flags[0] = (__popcll(m) < 32) ? 1u : 0u;          // isf32
    flags[1] = ((z & 0xFFull) == 0xFFull) ? 1u : 0u;  // is64
  }
}

// ---------------- CSR build ----------------

__global__ __launch_bounds__(256) void count_kernel(const void* __restrict__ ei,
    const void* __restrict__ batch, uint32* __restrict__ deg, uint32* __restrict__ gcnt,
    const uint32* __restrict__ flags)
{
  uint32 is64 = flags[1];
  int t = blockIdx.x*256 + threadIdx.x;
  if (t < N_EDGES) atomicAdd(&deg[ld_idx(ei, is64, (size_t)N_EDGES + t)], 1u);
  if (t < N_NODES) atomicAdd(&gcnt[ld_idx(batch, is64, t)], 1u);
}

__global__ __launch_bounds__(256) void scan_block_kernel(const uint32* __restrict__ deg,
    uint32* __restrict__ rowstart, uint32* __restrict__ bsum)
{
  __shared__ uint32 lds[256];
  int t = threadIdx.x;
  int i = blockIdx.x*256 + t;
  uint32 v = (i < N_NODES) ? deg[i] : 0u;
  uint32 x = v;
  lds[t] = x; __syncthreads();
  for (int off = 1; off < 256; off <<= 1){
    uint32 y = (t >= off) ? lds[t - off] : 0u;
    __syncthreads();
    x += y; lds[t] = x;
    __syncthreads();
  }
  if (i < N_NODES) rowstart[i] = x - v;      // exclusive, pre-offset
  if (t == 255) bsum[blockIdx.x] = x;
}

__global__ __launch_bounds__(256) void scan_top_kernel(const uint32* __restrict__ bsum,
    uint32* __restrict__ boff, const uint32* __restrict__ gcnt, uint32* __restrict__ gstart, int nb)
{
  __shared__ uint32 lds[256];
  int t = threadIdx.x;
  uint32 v = (t < nb) ? bsum[t] : 0u;
  uint32 x = v;
  lds[t] = x; __syncthreads();
  for (int off = 1; off < 256; off <<= 1){
    uint32 y = (t >= off) ? lds[t - off] : 0u;
    __syncthreads();
    x += y; lds[t] = x;
    __syncthreads();
  }
  boff[t] = x - v;
  __syncthreads();
  uint32 v2 = (t < NGRAPH) ? gcnt[t] : 0u;   // batch is sorted -> graphs are contiguous
  uint32 x2 = v2;
  lds[t] = x2; __syncthreads();
  for (int off = 1; off < 256; off <<= 1){
    uint32 y = (t >= off) ? lds[t - off] : 0u;
    __syncthreads();
    x2 += y; lds[t] = x2;
    __syncthreads();
  }
  if (t < NGRAPH) gstart[t] = x2 - v2;
}

__global__ __launch_bounds__(256) void scan_add_kernel(uint32* __restrict__ rowstart,
    const uint32* __restrict__ boff, uint32* __restrict__ cursor)
{
  int i = blockIdx.x*256 + threadIdx.x;
  if (i >= N_NODES) return;
  uint32 r = rowstart[i] + boff[i >> 8];
  rowstart[i] = r;
  cursor[i] = r;
}

__global__ __launch_bounds__(256) void fill_kernel(const void* __restrict__ ei,
    uint32* __restrict__ cursor, uint32* __restrict__ colidx, const uint32* __restrict__ flags)
{
  uint32 is64 = flags[1];
  int t = blockIdx.x*256 + threadIdx.x;
  if (t >= N_EDGES) return;
  int d = ld_idx(ei, is64, (size_t)N_EDGES + t);
  uint32 p = atomicAdd(&cursor[d], 1u);
  colidx[p] = (uint32)ld_idx(ei, is64, t);
}

// ---------------- mean aggregation (pull, CSR, no atomics) ----------------
// 16 lanes per node, 8 feats per lane. Output always bf16 (internal).

__global__ __launch_bounds__(256) void agg_kernel(const void* __restrict__ X, int x_ext,
    const uint32* __restrict__ rowstart, const uint32* __restrict__ deg,
    const uint32* __restrict__ colidx, ushort16* __restrict__ out,
    const uint32* __restrict__ flags)
{
  uint32 isf32 = x_ext ? flags[0] : 0u;
  int t = blockIdx.x*256 + threadIdx.x;
  int node = t >> 4;
  int l = t & 15;
  if (node >= N_NODES) return;
  uint32 st = rowstart[node];
  uint32 d  = deg[node];
  float a0=0,a1=0,a2=0,a3=0,a4=0,a5=0,a6=0,a7=0;
  if (!isf32){
    const ushort16* Xb = (const ushort16*)X;
    for (uint32 j = 0; j < d; ++j){
      uint32 s = colidx[st + j];
      const uint4 v = *(const uint4*)(Xb + (size_t)s*FD + l*8);
      a0 += bf2f_lo(v.x); a1 += bf2f_hi(v.x);
      a2 += bf2f_lo(v.y); a3 += bf2f_hi(v.y);
      a4 += bf2f_lo(v.z); a5 += bf2f_hi(v.z);
      a6 += bf2f_lo(v.w); a7 += bf2f_hi(v.w);
    }
  } else {
    const float* Xf = (const float*)X;
    for (uint32 j = 0; j < d; ++j){
      uint32 s = colidx[st + j];
      const float* p = Xf + (size_t)s*FD + l*8;
      float4 u = *(const float4*)p;
      float4 v = *(const float4*)(p + 4);
      a0 += u.x; a1 += u.y; a2 += u.z; a3 += u.w;
      a4 += v.x; a5 += v.y; a6 += v.z; a7 += v.w;
    }
  }
  float inv = 1.f / fmaxf((float)d, 1.f);
  uint4 o;
  o.x = (uint32)f2bf(a0*inv) | ((uint32)f2bf(a1*inv) << 16);
  o.y = (uint32)f2bf(a2*inv) | ((uint32)f2bf(a3*inv) << 16);
  o.z = (uint32)f2bf(a4*inv) | ((uint32)f2bf(a5*inv) << 16);
  o.w = (uint32)f2bf(a6*inv) | ((uint32)f2bf(a7*inv) << 16);
  *(uint4*)(out + (size_t)node*FD + l*8) = o;
}

// ---------------- fused GEMM + bias + BN-stat accumulation ----------------
// hpre[M,128] = [A0 | A1] (M x 256) @ [WL ; WR] (256 x 128) + bias
// MFMA 16x16x32 bf16. W staged in LDS in exact B-fragment order
// [ks][nt][lane][8] -> ds_read_b128 linear & conflict-free. Two 32 KiB
// phases (WL then WR): static LDS 32768 B.

__device__ __forceinline__ short8 lda_frag(const void* src, uint32 sf, size_t m, int koff){
  if (!sf) return *(const short8*)((const short*)src + m*FD + koff);
  const float* p = (const float*)src + m*FD + koff;
  float4 u = *(const float4*)p;
  float4 v = *(const float4*)(p + 4);
  short8 r;
  r[0]=(short)f2bf(u.x); r[1]=(short)f2bf(u.y); r[2]=(short)f2bf(u.z); r[3]=(short)f2bf(u.w);
  r[4]=(short)f2bf(v.x); r[5]=(short)f2bf(v.y); r[6]=(short)f2bf(v.z); r[7]=(short)f2bf(v.w);
  return r;
}

__global__ __launch_bounds__(256) void gemm_bn_kernel(
    const ushort16* __restrict__ A0, const void* __restrict__ A1, int a1_ext,
    const void* __restrict__ WL, const void* __restrict__ WR,
    const void* __restrict__ bias, const uint32* __restrict__ flags,
    float* __restrict__ hpre, float* __restrict__ bnsum, float* __restrict__ bnsq)
{
  __shared__ short ldsW[128*128];               // 32768 B
  uint32 isf32 = flags[0];
  uint32 a1f = a1_ext ? isf32 : 0u;
  int tid = threadIdx.x;
  int wave = tid >> 6, lane = tid & 63, lq = lane >> 4, lm = lane & 15;
  int mt0 = blockIdx.x*8 + wave*2;
  int mt1 = mt0 + 1;
  bool v0 = mt0 < MTILES, v1 = mt1 < MTILES;
  f32x4 acc0[8], acc1[8];
#pragma unroll
  for (int i = 0; i < 8; ++i){ acc0[i] = (f32x4){0.f,0.f,0.f,0.f}; acc1[i] = (f32x4){0.f,0.f,0.f,0.f}; }
  size_t m0 = (size_t)((v0 ? mt0 : 0)*16 + lm);
  size_t m1 = (size_t)((v1 ? mt1 : 0)*16 + lm);

  for (int ph = 0; ph < 2; ++ph){
    const void* w = (ph == 0) ? WL : WR;
    const void* src = (ph == 0) ? (const void*)A0 : A1;
    uint32 sf = (ph == 0) ? 0u : a1f;
    if (ph) __syncthreads();                    // everyone done reading phase-0 LDS
    for (int idx = tid; idx < 128*128; idx += 256){
      int k = idx >> 7, n = idx & 127;          // coalesced global read (n fastest)
      short wv = isf32 ? (short)f2bf(((const float*)w)[k*128 + n])
                       : ((const short*)w)[k*128 + n];
      // B-fragment order: frag lane = (n&15) + 16*((k>>3)&3); elem j = k&7
      int off = (((k >> 5)*8 + (n >> 4))*64 + (n & 15) + 16*((k >> 3) & 3))*8 + (k & 7);
      ldsW[off] = wv;
    }
    __syncthreads();

#pragma unroll
    for (int ks = 0; ks < 4; ++ks){
      int koff = ks*32 + lq*8;
      short8 a0 = lda_frag(src, sf, m0, koff);
      short8 a1 = lda_frag(src, sf, m1, koff);
#pragma unroll
      for (int nt = 0; nt < 8; ++nt){
        short8 b = *(const short8*)&ldsW[((ks*8 + nt)*64 + lane)*8];
        acc0[nt] = __builtin_amdgcn_mfma_f32_16x16x32_bf16(a0, b, acc0[nt], 0, 0, 0);
        acc1[nt] = __builtin_amdgcn_mfma_f32_16x16x32_bf16(a1, b, acc1[nt], 0, 0, 0);
      }
    }
  }

#pragma unroll
  for (int nt = 0; nt < 8; ++nt){
    int colc = nt*16 + lm;                      // C/D: col = lane&15
    float bb = ld_f(bias, isf32, colc);
    float s = 0.f, s2 = 0.f;
    if (v0){
      size_t nb = (size_t)(mt0*16 + lq*4);      // C/D: row = quad*4 + reg
#pragma unroll
      for (int r = 0; r < 4; ++r){
        float val = acc0[nt][r] + bb;
        hpre[(nb + r)*FD + colc] = val;
        s += val; s2 += val*val;
      }
    }
    if (v1){
      size_t nb = (size_t)(mt1*16 + lq*4);
#pragma unroll
      for (int r = 0; r < 4; ++r){
        float val = acc1[nt][r] + bb;
        hpre[(nb + r)*FD + colc] = val;
        s += val; s2 += val*val;
      }
    }
    s  += __shfl_xor(s, 16);  s  += __shfl_xor(s, 32);
    s2 += __shfl_xor(s2, 16); s2 += __shfl_xor(s2, 32);
    if (lq == 0){
      atomicAdd(&bnsum[colc], s);
      atomicAdd(&bnsq[colc], s2);
    }
  }
}

// ---------------- BN finalize / apply / pool ----------------

__global__ void bn_final_kernel(const float* __restrict__ bnsum, const float* __restrict__ bnsq,
    const void* __restrict__ gamma, const void* __restrict__ beta,
    const uint32* __restrict__ flags, float* __restrict__ scale, float* __restrict__ shift)
{
  uint32 isf32 = flags[0];
  int f = threadIdx.x;
  const float invN = 1.0f / (float)N_NODES;
  float mu  = bnsum[f] * invN;
  float var = bnsq[f] * invN - mu*mu;
  float sc  = ld_f(gamma, isf32, f) * rsqrtf(var + 1e-5f);
  scale[f] = sc;
  shift[f] = ld_f(beta, isf32, f) - mu * sc;
}

__global__ __launch_bounds__(256) void bn_apply_kernel(const float* __restrict__ hpre,
    const float* __restrict__ scale, const float* __restrict__ shift, ushort16* __restrict__ h1)
{
  int t = blockIdx.x*256 + threadIdx.x;          // t < N*128/4
  int e = t*4;
  int c = e & 127;
  float4 v = *(const float4*)(hpre + e);
  float r0 = fmaxf(v.x*scale[c+0] + shift[c+0], 0.f);
  float r1 = fmaxf(v.y*scale[c+1] + shift[c+1], 0.f);
  float r2 = fmaxf(v.z*scale[c+2] + shift[c+2], 0.f);
  float r3 = fmaxf(v.w*scale[c+3] + shift[c+3], 0.f);
  uint2 o;
  o.x = (uint32)f2bf(r0) | ((uint32)f2bf(r1) << 16);
  o.y = (uint32)f2bf(r2) | ((uint32)f2bf(r3) << 16);
  *(uint2*)(h1 + e) = o;
}

// Layer-2 BN + ReLU fused into pooling; h2 never materialized.
__global__ __launch_bounds__(128) void pool_partial_kernel(const float* __restrict__ hpre,
    const float* __restrict__ scale, const float* __restrict__ shift,
    const uint32* __restrict__ gstart, const uint32* __restrict__ gcnt, float* __restrict__ pool)
{
  int g = blockIdx.x >> 2, chunk = blockIdx.x & 3, f = threadIdx.x;
  uint32 st = gstart[g], c = gcnt[g];
  uint32 per = (c + 3) >> 2;
  uint32 b0 = st + chunk*per;
  uint32 b1 = b0 + per;
  uint32 e1 = st + c;
  if (b1 > e1) b1 = e1;
  float sc = scale[f], sh = shift[f], acc = 0.f;
  for (uint32 n = b0; n < b1; ++n)
    acc += fmaxf(hpre[(size_t)n*FD + f]*sc + sh, 0.f);
  atomicAdd(&pool[g*FD + f], acc);
}

__global__ void pool_final_kernel(const float* __restrict__ pool,
    const uint32* __restrict__ gcnt, void* __restrict__ out, const uint32* __restrict__ flags)
{
  uint32 isf32 = flags[0];
  int t = blockIdx.x*256 + threadIdx.x;          // t < 8192
  int g = t >> 7;
  float c = fmaxf((float)gcnt[g], 1.f);
  float v = pool[t] / c;
  if (isf32) ((float*)out)[t] = v;
  else       ((ushort16*)out)[t] = f2bf(v);
}

// ---------------- launch ----------------

extern "C" void kernel_launch(void* const* d_in, const int* in_sizes, int n_in,
                              void* d_out, int out_size, void* d_ws, size_t ws_size,
                              hipStream_t stream)
{
  const void* x   = d_in[0];
  const void* ei  = d_in[1];
  const void* bat = d_in[2];
  const void* wl1 = d_in[3];
  const void* bl1 = d_in[4];
  const void* wr1 = d_in[5];
  const void* g1  = d_in[6];
  const void* be1 = d_in[7];
  const void* wl2 = d_in[8];
  const void* bl2 = d_in[9];
  const void* wr2 = d_in[10];
  const void* g2  = d_in[11];
  const void* be2 = d_in[12];
  char* ws = (char*)d_ws;

  // workspace layout (all 16B-aligned; zeroed region first)
  uint32* deg    = (uint32*)(ws + 0);          // 50000 u32
  uint32* gcnt   = (uint32*)(ws + 200000);     // 64 u32
  float*  bn1s   = (float*) (ws + 200256);     // 128 f32
  float*  bn1q   = (float*) (ws + 200768);
  float*  bn2s   = (float*) (ws + 201280);
  float*  bn2q   = (float*) (ws + 201792);
  float*  pool   = (float*) (ws + 202304);     // 8192 f32 -> ends 235072
  uint32* flags  = (uint32*)(ws + 235072);     // 2 u32 (written by detect)
  uint32* rowstart = (uint32*)(ws + 235328);   // 50000 u32
  uint32* cursor   = (uint32*)(ws + 435328);   // 50000 u32
  uint32* bsum     = (uint32*)(ws + 635328);   // 256 u32
  uint32* boff     = (uint32*)(ws + 636352);   // 256 u32
  uint32* gstart   = (uint32*)(ws + 637376);   // 64 u32
  uint32* colidx   = (uint32*)(ws + 637632);   // 800000 u32 -> 3837632
  float*  scale1   = (float*) (ws + 3837632);
  float*  shift1   = (float*) (ws + 3838144);
  float*  scale2   = (float*) (ws + 3838656);
  float*  shift2   = (float*) (ws + 3839168);
  ushort16* agg    = (ushort16*)(ws + 3839744);   // 6.4M bf16 -> 16639744
  ushort16* h1     = (ushort16*)(ws + 16639744);  // 6.4M bf16 -> 29439744
  float*   hpre    = (float*)  (ws + 29439744);   // 6.4M f32  -> 55039744

  hipMemsetAsync(ws, 0, 235072, stream);

  detect_kernel    <<<1,    64,  0, stream>>>((const uint32*)x, (const uint32*)ei, flags);
  count_kernel     <<<3125, 256, 0, stream>>>(ei, bat, deg, gcnt, flags);
  scan_block_kernel<<<196,  256, 0, stream>>>(deg, rowstart, bsum);
  scan_top_kernel  <<<1,    256, 0, stream>>>(bsum, boff, gcnt, gstart, 196);
  scan_add_kernel  <<<196,  256, 0, stream>>>(rowstart, boff, cursor);
  fill_kernel      <<<3125, 256, 0, stream>>>(ei, cursor, colidx, flags);

  // layer 1
  agg_kernel    <<<3125, 256, 0, stream>>>(x, 1, rowstart, deg, colidx, agg, flags);
  gemm_bn_kernel<<<391,  256, 0, stream>>>(agg, x, 1, wl1, wr1, bl1, flags, hpre, bn1s, bn1q);
  bn_final_kernel<<<1,   128, 0, stream>>>(bn1s, bn1q, g1, be1, flags, scale1, shift1);
  bn_apply_kernel<<<6250,256, 0, stream>>>(hpre, scale1, shift1, h1);

  // layer 2
  agg_kernel    <<<3125, 256, 0, stream>>>(h1, 0, rowstart, deg, colidx, agg, flags);
  gemm_bn_kernel<<<391,  256, 0, stream>>>(agg, h1, 0, wl2, wr2, bl2, flags, hpre, bn2s, bn2q);
  bn_final_kernel<<<1,   128, 0, stream>>>(bn2s, bn2q, g2, be2, flags, scale2, shift2);

  // pool (BN2 + ReLU fused)
  pool_partial_kernel<<<256, 128, 0, stream>>>(hpre, scale2, shift2, gstart, gcnt, pool);
  pool_final_kernel  <<<32,  256, 0, stream>>>(pool, gcnt, d_out, flags);
}

// Round 4
// 470.135 us; speedup vs baseline: 1.5924x; 1.5924x over previous
//
#include <hip/hip_runtime.h>
#include <hip/hip_bf16.h>
#include <stdint.h>

typedef unsigned int uint32;
typedef unsigned short ushort16;

typedef __attribute__((ext_vector_type(8))) short short8;
typedef __attribute__((ext_vector_type(4))) float f32x4;

#define N_NODES 50000
#define N_EDGES 800000
#define FD      128
#define NGRAPH  64
#define MTILES  3125   // N_NODES / 16 exactly
#define NBK     196    // coarse buckets = ceil(50000/256)
#define GB      391    // gemm blocks / sort blocks (2048 edges each)

__device__ __forceinline__ float bf2f(ushort16 u){
  union { uint32 i; float f; } v; v.i = ((uint32)u) << 16; return v.f;
}
__device__ __forceinline__ float bf2f_lo(uint32 w){ union{uint32 i;float f;}v; v.i = w << 16; return v.f; }
__device__ __forceinline__ float bf2f_hi(uint32 w){ union{uint32 i;float f;}v; v.i = w & 0xffff0000u; return v.f; }
__device__ __forceinline__ ushort16 f2bf(float f){
  uint32 u = __float_as_uint(f);
  u += 0x7fffu + ((u >> 16) & 1u);   // round-to-nearest-even
  return (ushort16)(u >> 16);
}

// flags[0] = 1 iff float inputs are f32 (else bf16); flags[1] = 1 iff indices are int64
__device__ __forceinline__ int ld_idx(const void* p, uint32 is64, size_t i){
  return is64 ? (int)((const long long*)p)[i] : ((const int*)p)[i];
}
__device__ __forceinline__ float ld_f(const void* p, uint32 isf32, int i){
  return isf32 ? ((const float*)p)[i] : bf2f(((const ushort16*)p)[i]);
}

// ---------------- dtype detection (device-side, 1 wave) ----------------

__global__ void detect_kernel(const uint32* __restrict__ xw, const uint32* __restrict__ eiw,
                              uint32* __restrict__ flags)
{
  int t = threadIdx.x;                       // 64 lanes
  uint32 w = xw[t];
  uint32 e8 = (w >> 7) & 0xFFu;              // exponent field of the LOW bf16 half
  bool bf_like = (e8 >= 0x70u && e8 <= 0x82u);
  unsigned long long m = __ballot(bf_like);
  uint32 hi = (t < 8) ? eiw[2*t + 1] : 1u;
  unsigned long long z = __ballot(hi == 0u);
  if (t == 0){
    flags[0] = (__popcll(m) < 32) ? 1u : 0u;          // isf32
    flags[1] = ((z & 0xFFull) == 0xFFull) ? 1u : 0u;  // is64
  }
}

// ---------------- CSR build: atomic-free 2-level bucket sort ----------------
// pack = (dst<<16)|src.  Coarse bucket = dst>>8 (196 buckets, ~4k edges each).
// K1: pack + per-block LDS hist -> hist[blk][256]
// K2: one block: column sums, scan, per-block offsets off[blk][256], bbase[197]
// K3: scatter pack0 -> pack1 (bucket-contiguous) via LDS cursors
// K4: one block per bucket: LDS count+scan over 256 fine nodes -> rowstart/deg/colidx

__global__ __launch_bounds__(256) void pack_hist_kernel(const void* __restrict__ ei,
    const uint32* __restrict__ flags, uint32* __restrict__ pack0, uint32* __restrict__ hist)
{
  __shared__ uint32 h[256];
  uint32 is64 = flags[1];
  int tid = threadIdx.x;
  h[tid] = 0u;
  __syncthreads();
  int base = blockIdx.x*2048;
  for (int r = 0; r < 8; ++r){
    int i = base + r*256 + tid;
    if (i < N_EDGES){
      uint32 s = (uint32)ld_idx(ei, is64, i);
      uint32 d = (uint32)ld_idx(ei, is64, (size_t)N_EDGES + i);
      pack0[i] = (d << 16) | s;
      atomicAdd(&h[d >> 8], 1u);             // LDS atomic
    }
  }
  __syncthreads();
  hist[blockIdx.x*256 + tid] = h[tid];
}

__global__ __launch_bounds__(256) void scan_hist_kernel(const uint32* __restrict__ hist,
    uint32* __restrict__ off, uint32* __restrict__ bbase)
{
  __shared__ uint32 lds[256];
  int b = threadIdx.x;
  uint32 sum = 0;
  for (int k = 0; k < GB; ++k) sum += hist[k*256 + b];   // coalesced per k
  uint32 x = sum;
  lds[b] = x; __syncthreads();
  for (int o = 1; o < 256; o <<= 1){
    uint32 y = (b >= o) ? lds[b - o] : 0u;
    __syncthreads();
    x += y; lds[b] = x;
    __syncthreads();
  }
  uint32 base = x - sum;                      // exclusive over buckets
  if (b <= NBK) bbase[b] = (b < NBK) ? base : (uint32)N_EDGES;
  uint32 run = base;
  for (int k = 0; k < GB; ++k){
    off[k*256 + b] = run;
    run += hist[k*256 + b];
  }
}

__global__ __launch_bounds__(256) void scatter_kernel(const uint32* __restrict__ pack0,
    const uint32* __restrict__ off, uint32* __restrict__ pack1)
{
  __shared__ uint32 cur[256];
  int tid = threadIdx.x;
  cur[tid] = off[blockIdx.x*256 + tid];
  __syncthreads();
  int base = blockIdx.x*2048;
  for (int r = 0; r < 8; ++r){
    int i = base + r*256 + tid;
    if (i < N_EDGES){
      uint32 p = pack0[i];
      uint32 pos = atomicAdd(&cur[p >> 24], 1u);   // LDS atomic
      pack1[pos] = p;
    }
  }
}

__global__ __launch_bounds__(256) void bucket_csr_kernel(const uint32* __restrict__ pack1,
    const uint32* __restrict__ bbase, uint32* __restrict__ rowstart,
    uint32* __restrict__ deg, ushort16* __restrict__ colidx)
{
  __shared__ uint32 cnt[256];
  __shared__ uint32 lds[256];
  __shared__ uint32 cur[256];
  int tid = threadIdx.x;
  int bk = blockIdx.x;
  uint32 e0 = bbase[bk], e1 = bbase[bk + 1];
  cnt[tid] = 0u;
  __syncthreads();
  for (uint32 i = e0 + tid; i < e1; i += 256)
    atomicAdd(&cnt[(pack1[i] >> 16) & 255u], 1u);  // LDS atomic
  __syncthreads();
  uint32 v = cnt[tid];
  uint32 x = v;
  lds[tid] = x; __syncthreads();
  for (int o = 1; o < 256; o <<= 1){
    uint32 y = (tid >= o) ? lds[tid - o] : 0u;
    __syncthreads();
    x += y; lds[tid] = x;
    __syncthreads();
  }
  uint32 start = e0 + x - v;
  int node = bk*256 + tid;
  if (node < N_NODES){ rowstart[node] = start; deg[node] = v; }
  cur[tid] = start;
  __syncthreads();
  for (uint32 i = e0 + tid; i < e1; i += 256){
    uint32 p = pack1[i];
    uint32 pos = atomicAdd(&cur[(p >> 16) & 255u], 1u);  // LDS atomic
    colidx[pos] = (ushort16)(p & 0xFFFFu);
  }
}

// ---------------- graph segment boundaries (batch sorted, no atomics) -------

__global__ __launch_bounds__(256) void gseg_kernel(const void* __restrict__ batch,
    const uint32* __restrict__ flags, uint32* __restrict__ gstart)
{
  uint32 is64 = flags[1];
  int t = blockIdx.x*256 + threadIdx.x;
  if (t >= N_NODES) return;
  int b1 = ld_idx(batch, is64, t);
  int b0 = (t == 0) ? -1 : ld_idx(batch, is64, t - 1);
  for (int g = b0 + 1; g <= b1; ++g) gstart[g] = (uint32)t;
  if (t == N_NODES - 1)
    for (int g = b1 + 1; g <= NGRAPH; ++g) gstart[g] = (uint32)N_NODES;
}

// ---------------- mean aggregation (pull, CSR, no atomics) ----------------

__global__ __launch_bounds__(256) void agg_kernel(const void* __restrict__ X, int x_ext,
    const uint32* __restrict__ rowstart, const uint32* __restrict__ deg,
    const ushort16* __restrict__ colidx, ushort16* __restrict__ out,
    const uint32* __restrict__ flags)
{
  uint32 isf32 = x_ext ? flags[0] : 0u;
  int t = blockIdx.x*256 + threadIdx.x;
  int node = t >> 4;
  int l = t & 15;
  if (node >= N_NODES) return;
  uint32 st = rowstart[node];
  uint32 d  = deg[node];
  float a0=0,a1=0,a2=0,a3=0,a4=0,a5=0,a6=0,a7=0;
  if (!isf32){
    const ushort16* Xb = (const ushort16*)X;
    for (uint32 j = 0; j < d; ++j){
      uint32 s = colidx[st + j];
      const uint4 v = *(const uint4*)(Xb + (size_t)s*FD + l*8);
      a0 += bf2f_lo(v.x); a1 += bf2f_hi(v.x);
      a2 += bf2f_lo(v.y); a3 += bf2f_hi(v.y);
      a4 += bf2f_lo(v.z); a5 += bf2f_hi(v.z);
      a6 += bf2f_lo(v.w); a7 += bf2f_hi(v.w);
    }
  } else {
    const float* Xf = (const float*)X;
    for (uint32 j = 0; j < d; ++j){
      uint32 s = colidx[st + j];
      const float* p = Xf + (size_t)s*FD + l*8;
      float4 u = *(const float4*)p;
      float4 v = *(const float4*)(p + 4);
      a0 += u.x; a1 += u.y; a2 += u.z; a3 += u.w;
      a4 += v.x; a5 += v.y; a6 += v.z; a7 += v.w;
    }
  }
  float inv = 1.f / fmaxf((float)d, 1.f);
  uint4 o;
  o.x = (uint32)f2bf(a0*inv) | ((uint32)f2bf(a1*inv) << 16);
  o.y = (uint32)f2bf(a2*inv) | ((uint32)f2bf(a3*inv) << 16);
  o.z = (uint32)f2bf(a4*inv) | ((uint32)f2bf(a5*inv) << 16);
  o.w = (uint32)f2bf(a6*inv) | ((uint32)f2bf(a7*inv) << 16);
  *(uint4*)(out + (size_t)node*FD + l*8) = o;
}

// ---------------- fused GEMM + bias + BN-stat partials (no global atomics) --

__device__ __forceinline__ short8 lda_frag(const void* src, uint32 sf, size_t m, int koff){
  if (!sf) return *(const short8*)((const short*)src + m*FD + koff);
  const float* p = (const float*)src + m*FD + koff;
  float4 u = *(const float4*)p;
  float4 v = *(const float4*)(p + 4);
  short8 r;
  r[0]=(short)f2bf(u.x); r[1]=(short)f2bf(u.y); r[2]=(short)f2bf(u.z); r[3]=(short)f2bf(u.w);
  r[4]=(short)f2bf(v.x); r[5]=(short)f2bf(v.y); r[6]=(short)f2bf(v.z); r[7]=(short)f2bf(v.w);
  return r;
}

__global__ __launch_bounds__(256) void gemm_bn_kernel(
    const ushort16* __restrict__ A0, const void* __restrict__ A1, int a1_ext,
    const void* __restrict__ WL, const void* __restrict__ WR,
    const void* __restrict__ bias, const uint32* __restrict__ flags,
    float* __restrict__ hpre, float* __restrict__ bnpart)
{
  __shared__ short ldsW[128*128];               // 32768 B
  __shared__ float red[256];                    // [0..127]=sum, [128..255]=sumsq
  uint32 isf32 = flags[0];
  uint32 a1f = a1_ext ? isf32 : 0u;
  int tid = threadIdx.x;
  red[tid] = 0.f;
  int wave = tid >> 6, lane = tid & 63, lq = lane >> 4, lm = lane & 15;
  int mt0 = blockIdx.x*8 + wave*2;
  int mt1 = mt0 + 1;
  bool v0 = mt0 < MTILES, v1 = mt1 < MTILES;
  f32x4 acc0[8], acc1[8];
#pragma unroll
  for (int i = 0; i < 8; ++i){ acc0[i] = (f32x4){0.f,0.f,0.f,0.f}; acc1[i] = (f32x4){0.f,0.f,0.f,0.f}; }
  size_t m0 = (size_t)((v0 ? mt0 : 0)*16 + lm);
  size_t m1 = (size_t)((v1 ? mt1 : 0)*16 + lm);

  for (int ph = 0; ph < 2; ++ph){
    const void* w = (ph == 0) ? WL : WR;
    const void* src = (ph == 0) ? (const void*)A0 : A1;
    uint32 sf = (ph == 0) ? 0u : a1f;
    if (ph) __syncthreads();
    for (int idx = tid; idx < 128*128; idx += 256){
      int k = idx >> 7, n = idx & 127;
      short wv = isf32 ? (short)f2bf(((const float*)w)[k*128 + n])
                       : ((const short*)w)[k*128 + n];
      int off = (((k >> 5)*8 + (n >> 4))*64 + (n & 15) + 16*((k >> 3) & 3))*8 + (k & 7);
      ldsW[off] = wv;
    }
    __syncthreads();

#pragma unroll
    for (int ks = 0; ks < 4; ++ks){
      int koff = ks*32 + lq*8;
      short8 a0 = lda_frag(src, sf, m0, koff);
      short8 a1 = lda_frag(src, sf, m1, koff);
#pragma unroll
      for (int nt = 0; nt < 8; ++nt){
        short8 b = *(const short8*)&ldsW[((ks*8 + nt)*64 + lane)*8];
        acc0[nt] = __builtin_amdgcn_mfma_f32_16x16x32_bf16(a0, b, acc0[nt], 0, 0, 0);
        acc1[nt] = __builtin_amdgcn_mfma_f32_16x16x32_bf16(a1, b, acc1[nt], 0, 0, 0);
      }
    }
  }

#pragma unroll
  for (int nt = 0; nt < 8; ++nt){
    int colc = nt*16 + lm;                      // C/D: col = lane&15
    float bb = ld_f(bias, isf32, colc);
    float s = 0.f, s2 = 0.f;
    if (v0){
      size_t nb = (size_t)(mt0*16 + lq*4);      // C/D: row = quad*4 + reg
#pragma unroll
      for (int r = 0; r < 4; ++r){
        float val = acc0[nt][r] + bb;
        hpre[(nb + r)*FD + colc] = val;
        s += val; s2 += val*val;
      }
    }
    if (v1){
      size_t nb = (size_t)(mt1*16 + lq*4);
#pragma unroll
      for (int r = 0; r < 4; ++r){
        float val = acc1[nt][r] + bb;
        hpre[(nb + r)*FD + colc] = val;
        s += val; s2 += val*val;
      }
    }
    s  += __shfl_xor(s, 16);  s  += __shfl_xor(s, 32);
    s2 += __shfl_xor(s2, 16); s2 += __shfl_xor(s2, 32);
    if (lq == 0){
      atomicAdd(&red[colc], s);                 // LDS atomic (4-way, cheap)
      atomicAdd(&red[128 + colc], s2);
    }
  }
  __syncthreads();
  bnpart[blockIdx.x*256 + tid] = red[tid];
}

// ---------------- BN finalize (partials reduce) / apply / pool --------------

__global__ void bn_final_kernel(const float* __restrict__ bnpart,
    const void* __restrict__ gamma, const void* __restrict__ beta,
    const uint32* __restrict__ flags, float* __restrict__ scale, float* __restrict__ shift)
{
  uint32 isf32 = flags[0];
  int f = threadIdx.x;                          // 128
  float s = 0.f, q = 0.f;
  for (int b = 0; b < GB; ++b){
    s += bnpart[b*256 + f];
    q += bnpart[b*256 + 128 + f];
  }
  const float invN = 1.0f / (float)N_NODES;
  float mu  = s * invN;
  float var = q * invN - mu*mu;
  float sc  = ld_f(gamma, isf32, f) * rsqrtf(var + 1e-5f);
  scale[f] = sc;
  shift[f] = ld_f(beta, isf32, f) - mu * sc;
}

__global__ __launch_bounds__(256) void bn_apply_kernel(const float* __restrict__ hpre,
    const float* __restrict__ scale, const float* __restrict__ shift, ushort16* __restrict__ h1)
{
  int t = blockIdx.x*256 + threadIdx.x;          // t < N*128/4
  int e = t*4;
  int c = e & 127;
  float4 v = *(const float4*)(hpre + e);
  float r0 = fmaxf(v.x*scale[c+0] + shift[c+0], 0.f);
  float r1 = fmaxf(v.y*scale[c+1] + shift[c+1], 0.f);
  float r2 = fmaxf(v.z*scale[c+2] + shift[c+2], 0.f);
  float r3 = fmaxf(v.w*scale[c+3] + shift[c+3], 0.f);
  uint2 o;
  o.x = (uint32)f2bf(r0) | ((uint32)f2bf(r1) << 16);
  o.y = (uint32)f2bf(r2) | ((uint32)f2bf(r3) << 16);
  *(uint2*)(h1 + e) = o;
}

// Layer-2 BN + ReLU fused into pooling; partial sums, no atomics.
__global__ __launch_bounds__(128) void pool_partial_kernel(const float* __restrict__ hpre,
    const float* __restrict__ scale, const float* __restrict__ shift,
    const uint32* __restrict__ gstart, float* __restrict__ pool_part)
{
  int g = blockIdx.x >> 2, chunk = blockIdx.x & 3, f = threadIdx.x;
  uint32 st = gstart[g], c = gstart[g+1] - gstart[g];
  uint32 per = (c + 3) >> 2;
  uint32 b0 = st + chunk*per;
  uint32 b1 = b0 + per;
  uint32 e1 = st + c;
  if (b1 > e1) b1 = e1;
  float sc = scale[f], sh = shift[f], acc = 0.f;
  for (uint32 n = b0; n < b1; ++n)
    acc += fmaxf(hpre[(size_t)n*FD + f]*sc + sh, 0.f);
  pool_part[(size_t)blockIdx.x*FD + f] = acc;
}

__global__ void pool_final_kernel(const float* __restrict__ pool_part,
    const uint32* __restrict__ gstart, void* __restrict__ out, const uint32* __restrict__ flags)
{
  uint32 isf32 = flags[0];
  int t = blockIdx.x*256 + threadIdx.x;          // t < 8192
  int g = t >> 7, f = t & 127;
  float c = fmaxf((float)(gstart[g+1] - gstart[g]), 1.f);
  float v = (pool_part[(g*4+0)*FD + f] + pool_part[(g*4+1)*FD + f]
           + pool_part[(g*4+2)*FD + f] + pool_part[(g*4+3)*FD + f]) / c;
  if (isf32) ((float*)out)[t] = v;
  else       ((ushort16*)out)[t] = f2bf(v);
}

// ---------------- launch ----------------

extern "C" void kernel_launch(void* const* d_in, const int* in_sizes, int n_in,
                              void* d_out, int out_size, void* d_ws, size_t ws_size,
                              hipStream_t stream)
{
  const void* x   = d_in[0];
  const void* ei  = d_in[1];
  const void* bat = d_in[2];
  const void* wl1 = d_in[3];
  const void* bl1 = d_in[4];
  const void* wr1 = d_in[5];
  const void* g1  = d_in[6];
  const void* be1 = d_in[7];
  const void* wl2 = d_in[8];
  const void* bl2 = d_in[9];
  const void* wr2 = d_in[10];
  const void* g2  = d_in[11];
  const void* be2 = d_in[12];
  char* ws = (char*)d_ws;

  // persistent
  uint32* flags   = (uint32*)(ws + 0);            // 2 u32
  uint32* gstart  = (uint32*)(ws + 64);           // 65 u32
  uint32* bbase   = (uint32*)(ws + 384);          // 197 u32
  float*  bnpart  = (float*) (ws + 1280);         // 391*256 f32 -> 401,664
  float*  ppart   = (float*) (ws + 401664);       // 256*128 f32 -> 532,736
  float*  scale1  = (float*) (ws + 532736);
  float*  shift1  = (float*) (ws + 533248);
  float*  scale2  = (float*) (ws + 533760);
  float*  shift2  = (float*) (ws + 534272);
  uint32* rowstart= (uint32*)(ws + 534784);       // 50000 u32 -> 734,784
  uint32* deg     = (uint32*)(ws + 734784);       // 50000 u32 -> 934,784
  ushort16* colidx= (ushort16*)(ws + 934784);     // 800000 u16 -> 2,534,784
  ushort16* agg   = (ushort16*)(ws + 2534784);    // 12.8 MB -> 15,334,784
  ushort16* h1    = (ushort16*)(ws + 15334784);   // 12.8 MB -> 28,134,784
  float*   hpre   = (float*)  (ws + 28134784);    // 25.6 MB -> 53,734,784
  // transient (dead before hpre is first written by gemm_bn):
  uint32* pack0   = (uint32*)(ws + 28134784);     // 3.2 MB
  uint32* pack1   = (uint32*)(ws + 31334784);     // 3.2 MB
  uint32* hist    = (uint32*)(ws + 34534784);     // 391*256 u32
  uint32* off     = (uint32*)(ws + 34935168);     // 391*256 u32 -> 35,335,552

  detect_kernel    <<<1,   64,  0, stream>>>((const uint32*)x, (const uint32*)ei, flags);

  // CSR build (no global atomics)
  pack_hist_kernel <<<GB,  256, 0, stream>>>(ei, flags, pack0, hist);
  scan_hist_kernel <<<1,   256, 0, stream>>>(hist, off, bbase);
  scatter_kernel   <<<GB,  256, 0, stream>>>(pack0, off, pack1);
  bucket_csr_kernel<<<NBK, 256, 0, stream>>>(pack1, bbase, rowstart, deg, colidx);
  gseg_kernel      <<<196, 256, 0, stream>>>(bat, flags, gstart);

  // layer 1
  agg_kernel     <<<3125, 256, 0, stream>>>(x, 1, rowstart, deg, colidx, agg, flags);
  gemm_bn_kernel <<<GB,   256, 0, stream>>>(agg, x, 1, wl1, wr1, bl1, flags, hpre, bnpart);
  bn_final_kernel<<<1,    128, 0, stream>>>(bnpart, g1, be1, flags, scale1, shift1);
  bn_apply_kernel<<<6250, 256, 0, stream>>>(hpre, scale1, shift1, h1);

  // layer 2
  agg_kernel     <<<3125, 256, 0, stream>>>(h1, 0, rowstart, deg, colidx, agg, flags);
  gemm_bn_kernel <<<GB,   256, 0, stream>>>(agg, h1, 0, wl2, wr2, bl2, flags, hpre, bnpart);
  bn_final_kernel<<<1,    128, 0, stream>>>(bnpart, g2, be2, flags, scale2, shift2);

  // pool (BN2 + ReLU fused)
  pool_partial_kernel<<<256, 128, 0, stream>>>(hpre, scale2, shift2, gstart, ppart);
  pool_final_kernel  <<<32,  256, 0, stream>>>(ppart, gstart, d_out, flags);
}

// Round 5
// 372.454 us; speedup vs baseline: 2.0101x; 1.2623x over previous
//
#include <hip/hip_runtime.h>
#include <hip/hip_bf16.h>
#include <stdint.h>

typedef unsigned int uint32;
typedef unsigned short ushort16;

typedef __attribute__((ext_vector_type(8))) short short8;
typedef __attribute__((ext_vector_type(4))) float f32x4;

#define N_NODES 50000
#define N_EDGES 800000
#define FD      128
#define NGRAPH  64
#define MTILES  3125   // N_NODES / 16 exactly
#define NBK     196    // coarse buckets = ceil(50000/256)
#define GB      391    // gemm blocks / sort blocks (2048 edges each)

__device__ __forceinline__ float bf2f(ushort16 u){
  union { uint32 i; float f; } v; v.i = ((uint32)u) << 16; return v.f;
}
__device__ __forceinline__ float bf2f_lo(uint32 w){ union{uint32 i;float f;}v; v.i = w << 16; return v.f; }
__device__ __forceinline__ float bf2f_hi(uint32 w){ union{uint32 i;float f;}v; v.i = w & 0xffff0000u; return v.f; }
__device__ __forceinline__ ushort16 f2bf(float f){
  uint32 u = __float_as_uint(f);
  u += 0x7fffu + ((u >> 16) & 1u);   // round-to-nearest-even
  return (ushort16)(u >> 16);
}

// flags[0] = 1 iff float inputs are f32 (else bf16); flags[1] = 1 iff indices are int64
__device__ __forceinline__ int ld_idx(const void* p, uint32 is64, size_t i){
  return is64 ? (int)((const long long*)p)[i] : ((const int*)p)[i];
}
__device__ __forceinline__ float ld_f(const void* p, uint32 isf32, int i){
  return isf32 ? ((const float*)p)[i] : bf2f(((const ushort16*)p)[i]);
}

// ---------------- dtype detection (device-side, 1 wave) ----------------

__global__ void detect_kernel(const uint32* __restrict__ xw, const uint32* __restrict__ eiw,
                              uint32* __restrict__ flags)
{
  int t = threadIdx.x;                       // 64 lanes
  uint32 w = xw[t];
  uint32 e8 = (w >> 7) & 0xFFu;              // exponent field of the LOW bf16 half
  bool bf_like = (e8 >= 0x70u && e8 <= 0x82u);
  unsigned long long m = __ballot(bf_like);
  uint32 hi = (t < 8) ? eiw[2*t + 1] : 1u;
  unsigned long long z = __ballot(hi == 0u);
  if (t == 0){
    flags[0] = (__popcll(m) < 32) ? 1u : 0u;          // isf32
    flags[1] = ((z & 0xFFull) == 0xFFull) ? 1u : 0u;  // is64
  }
}

// ---------------- CSR build: atomic-free 2-level bucket sort ----------------

__global__ __launch_bounds__(256) void pack_hist_kernel(const void* __restrict__ ei,
    const uint32* __restrict__ flags, uint32* __restrict__ pack0, uint32* __restrict__ hist)
{
  __shared__ uint32 h[256];
  uint32 is64 = flags[1];
  int tid = threadIdx.x;
  h[tid] = 0u;
  __syncthreads();
  int base = blockIdx.x*2048;
  for (int r = 0; r < 8; ++r){
    int i = base + r*256 + tid;
    if (i < N_EDGES){
      uint32 s = (uint32)ld_idx(ei, is64, i);
      uint32 d = (uint32)ld_idx(ei, is64, (size_t)N_EDGES + i);
      pack0[i] = (d << 16) | s;
      atomicAdd(&h[d >> 8], 1u);             // LDS atomic
    }
  }
  __syncthreads();
  hist[blockIdx.x*256 + tid] = h[tid];
}

__global__ __launch_bounds__(256) void scan_hist_kernel(const uint32* __restrict__ hist,
    uint32* __restrict__ off, uint32* __restrict__ bbase)
{
  __shared__ uint32 lds[256];
  int b = threadIdx.x;
  uint32 sum = 0;
  for (int k = 0; k < GB; ++k) sum += hist[k*256 + b];
  uint32 x = sum;
  lds[b] = x; __syncthreads();
  for (int o = 1; o < 256; o <<= 1){
    uint32 y = (b >= o) ? lds[b - o] : 0u;
    __syncthreads();
    x += y; lds[b] = x;
    __syncthreads();
  }
  uint32 base = x - sum;
  if (b <= NBK) bbase[b] = (b < NBK) ? base : (uint32)N_EDGES;
  uint32 run = base;
  for (int k = 0; k < GB; ++k){
    off[k*256 + b] = run;
    run += hist[k*256 + b];
  }
}

__global__ __launch_bounds__(256) void scatter_kernel(const uint32* __restrict__ pack0,
    const uint32* __restrict__ off, uint32* __restrict__ pack1)
{
  __shared__ uint32 cur[256];
  int tid = threadIdx.x;
  cur[tid] = off[blockIdx.x*256 + tid];
  __syncthreads();
  int base = blockIdx.x*2048;
  for (int r = 0; r < 8; ++r){
    int i = base + r*256 + tid;
    if (i < N_EDGES){
      uint32 p = pack0[i];
      uint32 pos = atomicAdd(&cur[p >> 24], 1u);   // LDS atomic
      pack1[pos] = p;
    }
  }
}

__global__ __launch_bounds__(256) void bucket_csr_kernel(const uint32* __restrict__ pack1,
    const uint32* __restrict__ bbase, uint32* __restrict__ rowstart,
    uint32* __restrict__ deg, ushort16* __restrict__ colidx)
{
  __shared__ uint32 cnt[256];
  __shared__ uint32 lds[256];
  __shared__ uint32 cur[256];
  int tid = threadIdx.x;
  int bk = blockIdx.x;
  uint32 e0 = bbase[bk], e1 = bbase[bk + 1];
  cnt[tid] = 0u;
  __syncthreads();
  for (uint32 i = e0 + tid; i < e1; i += 256)
    atomicAdd(&cnt[(pack1[i] >> 16) & 255u], 1u);  // LDS atomic
  __syncthreads();
  uint32 v = cnt[tid];
  uint32 x = v;
  lds[tid] = x; __syncthreads();
  for (int o = 1; o < 256; o <<= 1){
    uint32 y = (tid >= o) ? lds[tid - o] : 0u;
    __syncthreads();
    x += y; lds[tid] = x;
    __syncthreads();
  }
  uint32 start = e0 + x - v;
  int node = bk*256 + tid;
  if (node < N_NODES){ rowstart[node] = start; deg[node] = v; }
  cur[tid] = start;
  __syncthreads();
  for (uint32 i = e0 + tid; i < e1; i += 256){
    uint32 p = pack1[i];
    uint32 pos = atomicAdd(&cur[(p >> 16) & 255u], 1u);  // LDS atomic
    colidx[pos] = (ushort16)(p & 0xFFFFu);
  }
}

// ---------------- graph segment boundaries (batch sorted) -------------------

__global__ __launch_bounds__(256) void gseg_kernel(const void* __restrict__ batch,
    const uint32* __restrict__ flags, uint32* __restrict__ gstart)
{
  uint32 is64 = flags[1];
  int t = blockIdx.x*256 + threadIdx.x;
  if (t >= N_NODES) return;
  int b1 = ld_idx(batch, is64, t);
  int b0 = (t == 0) ? -1 : ld_idx(batch, is64, t - 1);
  for (int g = b0 + 1; g <= b1; ++g) gstart[g] = (uint32)t;
  if (t == N_NODES - 1)
    for (int g = b1 + 1; g <= NGRAPH; ++g) gstart[g] = (uint32)N_NODES;
}

// ---------------- prep: x -> bf16, W -> bf16 B-fragment layout --------------

__global__ __launch_bounds__(256) void xcvt_kernel(const void* __restrict__ X,
    const uint32* __restrict__ flags, ushort16* __restrict__ xb)
{
  uint32 isf32 = flags[0];
  size_t e = ((size_t)blockIdx.x*256 + threadIdx.x)*8;   // 6.4M elems total
  if (isf32){
    const float* p = (const float*)X + e;
    float4 u = *(const float4*)p;
    float4 v = *(const float4*)(p + 4);
    uint4 o;
    o.x = (uint32)f2bf(u.x) | ((uint32)f2bf(u.y) << 16);
    o.y = (uint32)f2bf(u.z) | ((uint32)f2bf(u.w) << 16);
    o.z = (uint32)f2bf(v.x) | ((uint32)f2bf(v.y) << 16);
    o.w = (uint32)f2bf(v.z) | ((uint32)f2bf(v.w) << 16);
    *(uint4*)(xb + e) = o;
  } else {
    *(uint4*)(xb + e) = *(const uint4*)((const ushort16*)X + e);
  }
}

// W[k][n] (k in [0,256): k<128 -> WL, else WR) -> fragment order
// [ks(0..7)][nt(0..7)][lane(0..63)][j(0..7)], lane=(n&15)+16*((k>>3)&3), j=k&7
__global__ __launch_bounds__(256) void wprep_kernel(const void* __restrict__ WL1,
    const void* __restrict__ WR1, const void* __restrict__ WL2, const void* __restrict__ WR2,
    const uint32* __restrict__ flags, short* __restrict__ wfrag)
{
  uint32 isf32 = flags[0];
  int t = blockIdx.x*256 + threadIdx.x;   // 65536 total
  int layer = t >> 15;
  int r = t & 32767;
  int k = r >> 7, n = r & 127;
  const void* w = layer ? (k < 128 ? WL2 : WR2) : (k < 128 ? WL1 : WR1);
  int kk = k & 127;
  float wv = ld_f(w, isf32, kk*128 + n);
  int off = (((k >> 5)*8 + (n >> 4))*64 + (n & 15) + 16*((kk >> 3) & 3))*8 + (kk & 7);
  wfrag[layer*32768 + off] = (short)f2bf(wv);
}

// ---------------- mean aggregation (pull, CSR); APPLY fuses BN+ReLU --------

template<int APPLY>
__global__ __launch_bounds__(256) void agg_kernel(const ushort16* __restrict__ X,
    const uint32* __restrict__ rowstart, const uint32* __restrict__ deg,
    const ushort16* __restrict__ colidx,
    const float* __restrict__ sc, const float* __restrict__ sh,
    ushort16* __restrict__ out)
{
  int t = blockIdx.x*256 + threadIdx.x;
  int node = t >> 4;
  int l = t & 15;
  if (node >= N_NODES) return;
  uint32 st = rowstart[node];
  uint32 d  = deg[node];
  float s0[8], h0[8];
  if (APPLY){
#pragma unroll
    for (int j = 0; j < 8; ++j){ s0[j] = sc[l*8 + j]; h0[j] = sh[l*8 + j]; }
  }
  float a[8];
#pragma unroll
  for (int j = 0; j < 8; ++j) a[j] = 0.f;
  for (uint32 i = 0; i < d; ++i){
    uint32 s = colidx[st + i];
    const uint4 v = *(const uint4*)(X + (size_t)s*FD + l*8);
    float f[8];
    f[0] = bf2f_lo(v.x); f[1] = bf2f_hi(v.x);
    f[2] = bf2f_lo(v.y); f[3] = bf2f_hi(v.y);
    f[4] = bf2f_lo(v.z); f[5] = bf2f_hi(v.z);
    f[6] = bf2f_lo(v.w); f[7] = bf2f_hi(v.w);
#pragma unroll
    for (int j = 0; j < 8; ++j){
      float fv = APPLY ? fmaxf(f[j]*s0[j] + h0[j], 0.f) : f[j];
      a[j] += fv;
    }
  }
  float inv = 1.f / fmaxf((float)d, 1.f);
  uint4 o;
  o.x = (uint32)f2bf(a[0]*inv) | ((uint32)f2bf(a[1]*inv) << 16);
  o.y = (uint32)f2bf(a[2]*inv) | ((uint32)f2bf(a[3]*inv) << 16);
  o.z = (uint32)f2bf(a[4]*inv) | ((uint32)f2bf(a[5]*inv) << 16);
  o.w = (uint32)f2bf(a[6]*inv) | ((uint32)f2bf(a[7]*inv) << 16);
  *(uint4*)(out + (size_t)node*FD + l*8) = o;
}

// ---------------- fused GEMM + bias + BN-stat partials ----------------------
// hpre(bf16)[M,128] = [A0 | A1](M x 256, bf16) @ W(256x128, fragment layout in
// global, L2-hot) + bias.  No LDS staging, no K-loop barriers. APPLY applies
// BN1+ReLU to the A1 (h_i) operand on the fly.

__device__ __forceinline__ short8 affine_relu8(short8 a, const float* sc, const float* sh, int koff){
  short8 r;
#pragma unroll
  for (int j = 0; j < 8; ++j){
    float v = bf2f((ushort16)a[j]) * sc[koff + j] + sh[koff + j];
    r[j] = (short)f2bf(fmaxf(v, 0.f));
  }
  return r;
}

template<int APPLY>
__global__ __launch_bounds__(256) void gemm_bn_kernel(
    const ushort16* __restrict__ A0, const ushort16* __restrict__ A1,
    const short* __restrict__ wfrag, const void* __restrict__ bias,
    const uint32* __restrict__ flags,
    const float* __restrict__ sc, const float* __restrict__ sh,
    ushort16* __restrict__ hpre, float* __restrict__ bnpart)
{
  __shared__ float red[256];
  uint32 isf32 = flags[0];
  int tid = threadIdx.x;
  red[tid] = 0.f;
  int wave = tid >> 6, lane = tid & 63, lq = lane >> 4, lm = lane & 15;
  int mt0 = blockIdx.x*8 + wave*2;
  int mt1 = mt0 + 1;
  bool v0 = mt0 < MTILES, v1 = mt1 < MTILES;
  f32x4 acc0[8], acc1[8];
#pragma unroll
  for (int i = 0; i < 8; ++i){ acc0[i] = (f32x4){0.f,0.f,0.f,0.f}; acc1[i] = (f32x4){0.f,0.f,0.f,0.f}; }
  size_t m0 = (size_t)((v0 ? mt0 : 0)*16 + lm);
  size_t m1 = (size_t)((v1 ? mt1 : 0)*16 + lm);

#pragma unroll
  for (int ks = 0; ks < 8; ++ks){
    int koff = (ks & 3)*32 + lq*8;
    const short* srcp = (const short*)(ks < 4 ? A0 : A1);
    short8 a0 = *(const short8*)(srcp + m0*FD + koff);
    short8 a1 = *(const short8*)(srcp + m1*FD + koff);
    if (APPLY && ks >= 4){
      a0 = affine_relu8(a0, sc, sh, koff);
      a1 = affine_relu8(a1, sc, sh, koff);
    }
#pragma unroll
    for (int nt = 0; nt < 8; ++nt){
      short8 b = *(const short8*)&wfrag[((ks*8 + nt)*64 + lane)*8];
      acc0[nt] = __builtin_amdgcn_mfma_f32_16x16x32_bf16(a0, b, acc0[nt], 0, 0, 0);
      acc1[nt] = __builtin_amdgcn_mfma_f32_16x16x32_bf16(a1, b, acc1[nt], 0, 0, 0);
    }
  }

  __syncthreads();                              // red[] zero-init visible to all
#pragma unroll
  for (int nt = 0; nt < 8; ++nt){
    int colc = nt*16 + lm;                      // C/D: col = lane&15
    float bb = ld_f(bias, isf32, colc);
    float s = 0.f, s2 = 0.f;
    if (v0){
      size_t nb = (size_t)(mt0*16 + lq*4);      // C/D: row = quad*4 + reg
#pragma unroll
      for (int r = 0; r < 4; ++r){
        float val = acc0[nt][r] + bb;
        hpre[(nb + r)*FD + colc] = f2bf(val);
        s += val; s2 += val*val;
      }
    }
    if (v1){
      size_t nb = (size_t)(mt1*16 + lq*4);
#pragma unroll
      for (int r = 0; r < 4; ++r){
        float val = acc1[nt][r] + bb;
        hpre[(nb + r)*FD + colc] = f2bf(val);
        s += val; s2 += val*val;
      }
    }
    s  += __shfl_xor(s, 16);  s  += __shfl_xor(s, 32);
    s2 += __shfl_xor(s2, 16); s2 += __shfl_xor(s2, 32);
    if (lq == 0){
      atomicAdd(&red[colc], s);                 // LDS atomic
      atomicAdd(&red[128 + colc], s2);
    }
  }
  __syncthreads();
  bnpart[blockIdx.x*256 + tid] = red[tid];
}

// ---------------- BN finalize (partials reduce) -----------------------------

__global__ __launch_bounds__(1024) void bn_final_kernel(const float* __restrict__ bnpart,
    const void* __restrict__ gamma, const void* __restrict__ beta,
    const uint32* __restrict__ flags, float* __restrict__ scale, float* __restrict__ shift)
{
  __shared__ float ls[1024], lq2[1024];
  uint32 isf32 = flags[0];
  int tid = threadIdx.x, f = tid & 127, seg = tid >> 7;
  float s = 0.f, q = 0.f;
  for (int b = seg; b < GB; b += 8){
    s += bnpart[b*256 + f];
    q += bnpart[b*256 + 128 + f];
  }
  ls[tid] = s; lq2[tid] = q;
  __syncthreads();
  if (tid < 128){
#pragma unroll
    for (int k = 1; k < 8; ++k){ s += ls[k*128 + f]; q += lq2[k*128 + f]; }
    const float invN = 1.0f / (float)N_NODES;
    float mu  = s * invN;
    float var = q * invN - mu*mu;
    float scv = ld_f(gamma, isf32, f) * rsqrtf(var + 1e-5f);
    scale[f] = scv;
    shift[f] = ld_f(beta, isf32, f) - mu * scv;
  }
}

// ---------------- pool (BN2 + ReLU fused), partial sums ---------------------

__global__ __launch_bounds__(128) void pool_partial_kernel(const ushort16* __restrict__ hp,
    const float* __restrict__ scale, const float* __restrict__ shift,
    const uint32* __restrict__ gstart, float* __restrict__ pool_part)
{
  int g = blockIdx.x >> 2, chunk = blockIdx.x & 3, f = threadIdx.x;
  uint32 st = gstart[g], c = gstart[g+1] - gstart[g];
  uint32 per = (c + 3) >> 2;
  uint32 b0 = st + chunk*per;
  uint32 b1 = b0 + per;
  uint32 e1 = st + c;
  if (b1 > e1) b1 = e1;
  float sc = scale[f], sh = shift[f], acc = 0.f;
  for (uint32 n = b0; n < b1; ++n)
    acc += fmaxf(bf2f(hp[(size_t)n*FD + f])*sc + sh, 0.f);
  pool_part[(size_t)blockIdx.x*FD + f] = acc;
}

__global__ void pool_final_kernel(const float* __restrict__ pool_part,
    const uint32* __restrict__ gstart, void* __restrict__ out, const uint32* __restrict__ flags)
{
  uint32 isf32 = flags[0];
  int t = blockIdx.x*256 + threadIdx.x;          // t < 8192
  int g = t >> 7, f = t & 127;
  float c = fmaxf((float)(gstart[g+1] - gstart[g]), 1.f);
  float v = (pool_part[(g*4+0)*FD + f] + pool_part[(g*4+1)*FD + f]
           + pool_part[(g*4+2)*FD + f] + pool_part[(g*4+3)*FD + f]) / c;
  if (isf32) ((float*)out)[t] = v;
  else       ((ushort16*)out)[t] = f2bf(v);
}

// ---------------- launch ----------------

extern "C" void kernel_launch(void* const* d_in, const int* in_sizes, int n_in,
                              void* d_out, int out_size, void* d_ws, size_t ws_size,
                              hipStream_t stream)
{
  const void* x   = d_in[0];
  const void* ei  = d_in[1];
  const void* bat = d_in[2];
  const void* wl1 = d_in[3];
  const void* bl1 = d_in[4];
  const void* wr1 = d_in[5];
  const void* g1  = d_in[6];
  const void* be1 = d_in[7];
  const void* wl2 = d_in[8];
  const void* bl2 = d_in[9];
  const void* wr2 = d_in[10];
  const void* g2  = d_in[11];
  const void* be2 = d_in[12];
  char* ws = (char*)d_ws;

  // persistent
  uint32* flags   = (uint32*)(ws + 0);            // 2 u32
  uint32* gstart  = (uint32*)(ws + 64);           // 65 u32
  uint32* bbase   = (uint32*)(ws + 384);          // 197 u32
  float*  bnpart  = (float*) (ws + 1280);         // 391*256 f32 -> 401,664
  float*  ppart   = (float*) (ws + 401664);       // 256*128 f32 -> 532,736
  float*  scale1  = (float*) (ws + 532736);
  float*  shift1  = (float*) (ws + 533248);
  float*  scale2  = (float*) (ws + 533760);
  float*  shift2  = (float*) (ws + 534272);
  uint32* rowstart= (uint32*)(ws + 534784);       // -> 734,784
  uint32* deg     = (uint32*)(ws + 734784);       // -> 934,784
  ushort16* colidx= (ushort16*)(ws + 934784);     // u16 -> 2,534,784
  short*  wfrag   = (short*) (ws + 2534784);      // 2 x 32768 shorts -> 2,665,856
  ushort16* xb    = (ushort16*)(ws + 2665856);    // 12.8 MB -> 15,465,856
  ushort16* aggb  = (ushort16*)(ws + 15465856);   // 12.8 MB -> 28,265,856
  ushort16* hp1   = (ushort16*)(ws + 28265856);   // 12.8 MB -> 41,065,856
  ushort16* hp2   = (ushort16*)(ws + 41065856);   // 12.8 MB -> 53,865,856
  // transient (inside hp1/hp2 region, dead until gemm1 runs):
  uint32* pack0   = (uint32*)(ws + 28265856);     // 3.2 MB
  uint32* pack1   = (uint32*)(ws + 31465856);     // 3.2 MB
  uint32* hist    = (uint32*)(ws + 34665856);     // 391*256 u32
  uint32* off     = (uint32*)(ws + 35066240);     // 391*256 u32

  detect_kernel    <<<1,   64,  0, stream>>>((const uint32*)x, (const uint32*)ei, flags);

  // CSR build (no global atomics)
  pack_hist_kernel <<<GB,  256, 0, stream>>>(ei, flags, pack0, hist);
  scan_hist_kernel <<<1,   256, 0, stream>>>(hist, off, bbase);
  scatter_kernel   <<<GB,  256, 0, stream>>>(pack0, off, pack1);
  bucket_csr_kernel<<<NBK, 256, 0, stream>>>(pack1, bbase, rowstart, deg, colidx);
  gseg_kernel      <<<196, 256, 0, stream>>>(bat, flags, gstart);

  // prep
  xcvt_kernel      <<<3125, 256, 0, stream>>>(x, flags, xb);
  wprep_kernel     <<<256,  256, 0, stream>>>(wl1, wr1, wl2, wr2, flags, wfrag);

  // layer 1
  agg_kernel<0>    <<<3125, 256, 0, stream>>>(xb, rowstart, deg, colidx, nullptr, nullptr, aggb);
  gemm_bn_kernel<0><<<GB,   256, 0, stream>>>(aggb, xb, wfrag, bl1, flags, nullptr, nullptr, hp1, bnpart);
  bn_final_kernel  <<<1,   1024, 0, stream>>>(bnpart, g1, be1, flags, scale1, shift1);

  // layer 2 (BN1+ReLU fused into agg and into gemm's A1 operand)
  agg_kernel<1>    <<<3125, 256, 0, stream>>>(hp1, rowstart, deg, colidx, scale1, shift1, aggb);
  gemm_bn_kernel<1><<<GB,   256, 0, stream>>>(aggb, hp1, wfrag + 32768, bl2, flags, scale1, shift1, hp2, bnpart);
  bn_final_kernel  <<<1,   1024, 0, stream>>>(bnpart, g2, be2, flags, scale2, shift2);

  // pool (BN2 + ReLU fused)
  pool_partial_kernel<<<256, 128, 0, stream>>>(hp2, scale2, shift2, gstart, ppart);
  pool_final_kernel  <<<32,  256, 0, stream>>>(ppart, gstart, d_out, flags);
}

// Round 6
// 324.973 us; speedup vs baseline: 2.3038x; 1.1461x over previous
//
#include <hip/hip_runtime.h>
#include <hip/hip_bf16.h>
#include <stdint.h>

typedef unsigned int uint32;
typedef unsigned short ushort16;

typedef __attribute__((ext_vector_type(8))) short short8;
typedef __attribute__((ext_vector_type(4))) float f32x4;

#define N_NODES 50000
#define N_EDGES 800000
#define FD      128
#define NGRAPH  64
#define MTILES  3125   // N_NODES / 16 exactly
#define NBK     196    // coarse buckets = ceil(50000/256)
#define GB      391    // gemm blocks / sort blocks (2048 edges each)
#define PCH     32     // pool chunks per graph

__device__ __forceinline__ float bf2f(ushort16 u){
  union { uint32 i; float f; } v; v.i = ((uint32)u) << 16; return v.f;
}
__device__ __forceinline__ float bf2f_lo(uint32 w){ union{uint32 i;float f;}v; v.i = w << 16; return v.f; }
__device__ __forceinline__ float bf2f_hi(uint32 w){ union{uint32 i;float f;}v; v.i = w & 0xffff0000u; return v.f; }
__device__ __forceinline__ ushort16 f2bf(float f){
  uint32 u = __float_as_uint(f);
  u += 0x7fffu + ((u >> 16) & 1u);   // round-to-nearest-even
  return (ushort16)(u >> 16);
}

// flags[0] = 1 iff float inputs are f32 (else bf16); flags[1] = 1 iff indices are int64
__device__ __forceinline__ int ld_idx(const void* p, uint32 is64, size_t i){
  return is64 ? (int)((const long long*)p)[i] : ((const int*)p)[i];
}
__device__ __forceinline__ float ld_f(const void* p, uint32 isf32, int i){
  return isf32 ? ((const float*)p)[i] : bf2f(((const ushort16*)p)[i]);
}

// ---------------- dtype detection (device-side, 1 wave) ----------------

__global__ void detect_kernel(const uint32* __restrict__ xw, const uint32* __restrict__ eiw,
                              uint32* __restrict__ flags)
{
  int t = threadIdx.x;                       // 64 lanes
  uint32 w = xw[t];
  uint32 e8 = (w >> 7) & 0xFFu;              // exponent field of the LOW bf16 half
  bool bf_like = (e8 >= 0x70u && e8 <= 0x82u);
  unsigned long long m = __ballot(bf_like);
  uint32 hi = (t < 8) ? eiw[2*t + 1] : 1u;
  unsigned long long z = __ballot(hi == 0u);
  if (t == 0){
    flags[0] = (__popcll(m) < 32) ? 1u : 0u;          // isf32
    flags[1] = ((z & 0xFFull) == 0xFFull) ? 1u : 0u;  // is64
  }
}

// ---------------- CSR build: atomic-free 2-level bucket sort ----------------

__global__ __launch_bounds__(256) void pack_hist_kernel(const void* __restrict__ ei,
    const uint32* __restrict__ flags, uint32* __restrict__ pack0, uint32* __restrict__ hist)
{
  __shared__ uint32 h[256];
  uint32 is64 = flags[1];
  int tid = threadIdx.x;
  h[tid] = 0u;
  __syncthreads();
  int base = blockIdx.x*2048;
  for (int r = 0; r < 8; ++r){
    int i = base + r*256 + tid;
    if (i < N_EDGES){
      uint32 s = (uint32)ld_idx(ei, is64, i);
      uint32 d = (uint32)ld_idx(ei, is64, (size_t)N_EDGES + i);
      pack0[i] = (d << 16) | s;
      atomicAdd(&h[d >> 8], 1u);             // LDS atomic
    }
  }
  __syncthreads();
  hist[blockIdx.x*256 + tid] = h[tid];
}

__global__ __launch_bounds__(256) void scan_hist_kernel(const uint32* __restrict__ hist,
    uint32* __restrict__ off, uint32* __restrict__ bbase)
{
  __shared__ uint32 lds[256];
  int b = threadIdx.x;
  uint32 sum = 0;
  for (int k = 0; k < GB; ++k) sum += hist[k*256 + b];
  uint32 x = sum;
  lds[b] = x; __syncthreads();
  for (int o = 1; o < 256; o <<= 1){
    uint32 y = (b >= o) ? lds[b - o] : 0u;
    __syncthreads();
    x += y; lds[b] = x;
    __syncthreads();
  }
  uint32 base = x - sum;
  if (b <= NBK) bbase[b] = (b < NBK) ? base : (uint32)N_EDGES;
  uint32 run = base;
  for (int k = 0; k < GB; ++k){
    off[k*256 + b] = run;
    run += hist[k*256 + b];
  }
}

__global__ __launch_bounds__(256) void scatter_kernel(const uint32* __restrict__ pack0,
    const uint32* __restrict__ off, uint32* __restrict__ pack1)
{
  __shared__ uint32 cur[256];
  int tid = threadIdx.x;
  cur[tid] = off[blockIdx.x*256 + tid];
  __syncthreads();
  int base = blockIdx.x*2048;
  for (int r = 0; r < 8; ++r){
    int i = base + r*256 + tid;
    if (i < N_EDGES){
      uint32 p = pack0[i];
      uint32 pos = atomicAdd(&cur[p >> 24], 1u);   // LDS atomic
      pack1[pos] = p;
    }
  }
}

__global__ __launch_bounds__(256) void bucket_csr_kernel(const uint32* __restrict__ pack1,
    const uint32* __restrict__ bbase, uint32* __restrict__ rowstart,
    uint32* __restrict__ deg, ushort16* __restrict__ colidx)
{
  __shared__ uint32 cnt[256];
  __shared__ uint32 lds[256];
  __shared__ uint32 cur[256];
  int tid = threadIdx.x;
  int bk = blockIdx.x;
  uint32 e0 = bbase[bk], e1 = bbase[bk + 1];
  cnt[tid] = 0u;
  __syncthreads();
  for (uint32 i = e0 + tid; i < e1; i += 256)
    atomicAdd(&cnt[(pack1[i] >> 16) & 255u], 1u);  // LDS atomic
  __syncthreads();
  uint32 v = cnt[tid];
  uint32 x = v;
  lds[tid] = x; __syncthreads();
  for (int o = 1; o < 256; o <<= 1){
    uint32 y = (tid >= o) ? lds[tid - o] : 0u;
    __syncthreads();
    x += y; lds[tid] = x;
    __syncthreads();
  }
  uint32 start = e0 + x - v;
  int node = bk*256 + tid;
  if (node < N_NODES){ rowstart[node] = start; deg[node] = v; }
  cur[tid] = start;
  __syncthreads();
  for (uint32 i = e0 + tid; i < e1; i += 256){
    uint32 p = pack1[i];
    uint32 pos = atomicAdd(&cur[(p >> 16) & 255u], 1u);  // LDS atomic
    colidx[pos] = (ushort16)(p & 0xFFFFu);
  }
}

// ---------------- graph segment boundaries (batch sorted) -------------------

__global__ __launch_bounds__(256) void gseg_kernel(const void* __restrict__ batch,
    const uint32* __restrict__ flags, uint32* __restrict__ gstart)
{
  uint32 is64 = flags[1];
  int t = blockIdx.x*256 + threadIdx.x;
  if (t >= N_NODES) return;
  int b1 = ld_idx(batch, is64, t);
  int b0 = (t == 0) ? -1 : ld_idx(batch, is64, t - 1);
  for (int g = b0 + 1; g <= b1; ++g) gstart[g] = (uint32)t;
  if (t == N_NODES - 1)
    for (int g = b1 + 1; g <= NGRAPH; ++g) gstart[g] = (uint32)N_NODES;
}

// ---------------- prep: x -> bf16, W -> bf16 B-fragment layout --------------

__global__ __launch_bounds__(256) void xcvt_kernel(const void* __restrict__ X,
    const uint32* __restrict__ flags, ushort16* __restrict__ xb)
{
  uint32 isf32 = flags[0];
  size_t e = ((size_t)blockIdx.x*256 + threadIdx.x)*8;   // 6.4M elems total
  if (isf32){
    const float* p = (const float*)X + e;
    float4 u = *(const float4*)p;
    float4 v = *(const float4*)(p + 4);
    uint4 o;
    o.x = (uint32)f2bf(u.x) | ((uint32)f2bf(u.y) << 16);
    o.y = (uint32)f2bf(u.z) | ((uint32)f2bf(u.w) << 16);
    o.z = (uint32)f2bf(v.x) | ((uint32)f2bf(v.y) << 16);
    o.w = (uint32)f2bf(v.z) | ((uint32)f2bf(v.w) << 16);
    *(uint4*)(xb + e) = o;
  } else {
    *(uint4*)(xb + e) = *(const uint4*)((const ushort16*)X + e);
  }
}

// W[k][n] (k in [0,256): k<128 -> WL, else WR) -> fragment order
// [ks(0..7)][nt(0..7)][lane(0..63)][j(0..7)], lane=(n&15)+16*((k>>3)&3), j=k&7
__global__ __launch_bounds__(256) void wprep_kernel(const void* __restrict__ WL1,
    const void* __restrict__ WR1, const void* __restrict__ WL2, const void* __restrict__ WR2,
    const uint32* __restrict__ flags, short* __restrict__ wfrag)
{
  uint32 isf32 = flags[0];
  int t = blockIdx.x*256 + threadIdx.x;   // 65536 total
  int layer = t >> 15;
  int r = t & 32767;
  int k = r >> 7, n = r & 127;
  const void* w = layer ? (k < 128 ? WL2 : WR2) : (k < 128 ? WL1 : WR1);
  int kk = k & 127;
  float wv = ld_f(w, isf32, kk*128 + n);
  int off = (((k >> 5)*8 + (n >> 4))*64 + (n & 15) + 16*((kk >> 3) & 3))*8 + (kk & 7);
  wfrag[layer*32768 + off] = (short)f2bf(wv);
}

// ---------------- mean aggregation (pull, CSR); APPLY fuses BN+ReLU --------

template<int APPLY>
__global__ __launch_bounds__(256) void agg_kernel(const ushort16* __restrict__ X,
    const uint32* __restrict__ rowstart, const uint32* __restrict__ deg,
    const ushort16* __restrict__ colidx,
    const float* __restrict__ sc, const float* __restrict__ sh,
    ushort16* __restrict__ out)
{
  int t = blockIdx.x*256 + threadIdx.x;
  int node = t >> 4;
  int l = t & 15;
  if (node >= N_NODES) return;
  uint32 st = rowstart[node];
  uint32 d  = deg[node];
  float s0[8], h0[8];
  if (APPLY){
#pragma unroll
    for (int j = 0; j < 8; ++j){ s0[j] = sc[l*8 + j]; h0[j] = sh[l*8 + j]; }
  }
  float a[8];
#pragma unroll
  for (int j = 0; j < 8; ++j) a[j] = 0.f;
  for (uint32 i = 0; i < d; ++i){
    uint32 s = colidx[st + i];
    const uint4 v = *(const uint4*)(X + (size_t)s*FD + l*8);
    float f[8];
    f[0] = bf2f_lo(v.x); f[1] = bf2f_hi(v.x);
    f[2] = bf2f_lo(v.y); f[3] = bf2f_hi(v.y);
    f[4] = bf2f_lo(v.z); f[5] = bf2f_hi(v.z);
    f[6] = bf2f_lo(v.w); f[7] = bf2f_hi(v.w);
#pragma unroll
    for (int j = 0; j < 8; ++j){
      float fv = APPLY ? fmaxf(f[j]*s0[j] + h0[j], 0.f) : f[j];
      a[j] += fv;
    }
  }
  float inv = 1.f / fmaxf((float)d, 1.f);
  uint4 o;
  o.x = (uint32)f2bf(a[0]*inv) | ((uint32)f2bf(a[1]*inv) << 16);
  o.y = (uint32)f2bf(a[2]*inv) | ((uint32)f2bf(a[3]*inv) << 16);
  o.z = (uint32)f2bf(a[4]*inv) | ((uint32)f2bf(a[5]*inv) << 16);
  o.w = (uint32)f2bf(a[6]*inv) | ((uint32)f2bf(a[7]*inv) << 16);
  *(uint4*)(out + (size_t)node*FD + l*8) = o;
}

// ---------------- fused GEMM + bias + BN-stat partials ----------------------

__device__ __forceinline__ short8 affine_relu8(short8 a, const float* sc, const float* sh, int koff){
  short8 r;
#pragma unroll
  for (int j = 0; j < 8; ++j){
    float v = bf2f((ushort16)a[j]) * sc[koff + j] + sh[koff + j];
    r[j] = (short)f2bf(fmaxf(v, 0.f));
  }
  return r;
}

template<int APPLY>
__global__ __launch_bounds__(256) void gemm_bn_kernel(
    const ushort16* __restrict__ A0, const ushort16* __restrict__ A1,
    const short* __restrict__ wfrag, const void* __restrict__ bias,
    const uint32* __restrict__ flags,
    const float* __restrict__ sc, const float* __restrict__ sh,
    ushort16* __restrict__ hpre, float* __restrict__ bnpart)
{
  __shared__ float red[256];
  uint32 isf32 = flags[0];
  int tid = threadIdx.x;
  red[tid] = 0.f;
  int wave = tid >> 6, lane = tid & 63, lq = lane >> 4, lm = lane & 15;
  int mt0 = blockIdx.x*8 + wave*2;
  int mt1 = mt0 + 1;
  bool v0 = mt0 < MTILES, v1 = mt1 < MTILES;
  f32x4 acc0[8], acc1[8];
#pragma unroll
  for (int i = 0; i < 8; ++i){ acc0[i] = (f32x4){0.f,0.f,0.f,0.f}; acc1[i] = (f32x4){0.f,0.f,0.f,0.f}; }
  size_t m0 = (size_t)((v0 ? mt0 : 0)*16 + lm);
  size_t m1 = (size_t)((v1 ? mt1 : 0)*16 + lm);

#pragma unroll
  for (int ks = 0; ks < 8; ++ks){
    int koff = (ks & 3)*32 + lq*8;
    const short* srcp = (const short*)(ks < 4 ? A0 : A1);
    short8 a0 = *(const short8*)(srcp + m0*FD + koff);
    short8 a1 = *(const short8*)(srcp + m1*FD + koff);
    if (APPLY && ks >= 4){
      a0 = affine_relu8(a0, sc, sh, koff);
      a1 = affine_relu8(a1, sc, sh, koff);
    }
#pragma unroll
    for (int nt = 0; nt < 8; ++nt){
      short8 b = *(const short8*)&wfrag[((ks*8 + nt)*64 + lane)*8];
      acc0[nt] = __builtin_amdgcn_mfma_f32_16x16x32_bf16(a0, b, acc0[nt], 0, 0, 0);
      acc1[nt] = __builtin_amdgcn_mfma_f32_16x16x32_bf16(a1, b, acc1[nt], 0, 0, 0);
    }
  }

  __syncthreads();                              // red[] zero-init visible to all
#pragma unroll
  for (int nt = 0; nt < 8; ++nt){
    int colc = nt*16 + lm;                      // C/D: col = lane&15
    float bb = ld_f(bias, isf32, colc);
    float s = 0.f, s2 = 0.f;
    if (v0){
      size_t nb = (size_t)(mt0*16 + lq*4);      // C/D: row = quad*4 + reg
#pragma unroll
      for (int r = 0; r < 4; ++r){
        float val = acc0[nt][r] + bb;
        hpre[(nb + r)*FD + colc] = f2bf(val);
        s += val; s2 += val*val;
      }
    }
    if (v1){
      size_t nb = (size_t)(mt1*16 + lq*4);
#pragma unroll
      for (int r = 0; r < 4; ++r){
        float val = acc1[nt][r] + bb;
        hpre[(nb + r)*FD + colc] = f2bf(val);
        s += val; s2 += val*val;
      }
    }
    s  += __shfl_xor(s, 16);  s  += __shfl_xor(s, 32);
    s2 += __shfl_xor(s2, 16); s2 += __shfl_xor(s2, 32);
    if (lq == 0){
      atomicAdd(&red[colc], s);                 // LDS atomic
      atomicAdd(&red[128 + colc], s2);
    }
  }
  __syncthreads();
  bnpart[blockIdx.x*256 + tid] = red[tid];
}

// ---------------- BN finalize (partials reduce) -----------------------------

__global__ __launch_bounds__(1024) void bn_final_kernel(const float* __restrict__ bnpart,
    const void* __restrict__ gamma, const void* __restrict__ beta,
    const uint32* __restrict__ flags, float* __restrict__ scale, float* __restrict__ shift)
{
  __shared__ float ls[1024], lq2[1024];
  uint32 isf32 = flags[0];
  int tid = threadIdx.x, f = tid & 127, seg = tid >> 7;
  float s = 0.f, q = 0.f;
  for (int b = seg; b < GB; b += 8){
    s += bnpart[b*256 + f];
    q += bnpart[b*256 + 128 + f];
  }
  ls[tid] = s; lq2[tid] = q;
  __syncthreads();
  if (tid < 128){
#pragma unroll
    for (int k = 1; k < 8; ++k){ s += ls[k*128 + f]; q += lq2[k*128 + f]; }
    const float invN = 1.0f / (float)N_NODES;
    float mu  = s * invN;
    float var = q * invN - mu*mu;
    float scv = ld_f(gamma, isf32, f) * rsqrtf(var + 1e-5f);
    scale[f] = scv;
    shift[f] = ld_f(beta, isf32, f) - mu * scv;
  }
}

// ---------------- pool (BN2 + ReLU fused), high-occupancy -------------------
// 64 graphs x 32 chunks = 2048 blocks x 256 threads (full occupancy).
// Thread (slot=tid>>4, l=tid&15): uint4 loads of 8 feats, ~1-2 rows/thread.
// Reduce 16 slots: shfl over the 4 in-wave slots, LDS across the 4 waves.

__global__ __launch_bounds__(256) void pool_partial_kernel(const ushort16* __restrict__ hp,
    const float* __restrict__ scale, const float* __restrict__ shift,
    const uint32* __restrict__ gstart, float* __restrict__ pool_part)
{
  __shared__ float wred[4*16*8];                 // 2 KB
  int tid = threadIdx.x;
  int g = blockIdx.x >> 5, chunk = blockIdx.x & 31;
  int slot = tid >> 4, l = tid & 15;
  int wave = tid >> 6, lane = tid & 63;
  uint32 st = gstart[g], cnt = gstart[g+1] - st;
  uint32 per = (cnt + PCH - 1) >> 5;
  uint32 b0 = st + chunk*per;
  uint32 b1 = b0 + per;
  uint32 e1 = st + cnt;
  if (b1 > e1) b1 = e1;
  float s0[8], h0[8], a[8];
#pragma unroll
  for (int j = 0; j < 8; ++j){ s0[j] = scale[l*8 + j]; h0[j] = shift[l*8 + j]; a[j] = 0.f; }
  for (uint32 n = b0 + slot; n < b1; n += 16){
    const uint4 v = *(const uint4*)(hp + (size_t)n*FD + l*8);
    float f[8];
    f[0] = bf2f_lo(v.x); f[1] = bf2f_hi(v.x);
    f[2] = bf2f_lo(v.y); f[3] = bf2f_hi(v.y);
    f[4] = bf2f_lo(v.z); f[5] = bf2f_hi(v.z);
    f[6] = bf2f_lo(v.w); f[7] = bf2f_hi(v.w);
#pragma unroll
    for (int j = 0; j < 8; ++j) a[j] += fmaxf(f[j]*s0[j] + h0[j], 0.f);
  }
#pragma unroll
  for (int j = 0; j < 8; ++j){                   // reduce the 4 slots in this wave
    a[j] += __shfl_xor(a[j], 16);
    a[j] += __shfl_xor(a[j], 32);
  }
  if (lane < 16){
#pragma unroll
    for (int j = 0; j < 8; ++j) wred[(wave*16 + lane)*8 + j] = a[j];
  }
  __syncthreads();
  if (tid < 16){
    float r[8];
#pragma unroll
    for (int j = 0; j < 8; ++j)
      r[j] = wred[(0*16 + tid)*8 + j] + wred[(1*16 + tid)*8 + j]
           + wred[(2*16 + tid)*8 + j] + wred[(3*16 + tid)*8 + j];
    float* dst = pool_part + (size_t)blockIdx.x*FD + tid*8;
#pragma unroll
    for (int j = 0; j < 8; ++j) dst[j] = r[j];
  }
}

__global__ void pool_final_kernel(const float* __restrict__ pool_part,
    const uint32* __restrict__ gstart, void* __restrict__ out, const uint32* __restrict__ flags)
{
  uint32 isf32 = flags[0];
  int t = blockIdx.x*256 + threadIdx.x;          // t < 8192
  int g = t >> 7, f = t & 127;
  float c = fmaxf((float)(gstart[g+1] - gstart[g]), 1.f);
  float v = 0.f;
#pragma unroll 8
  for (int ch = 0; ch < PCH; ++ch)
    v += pool_part[(size_t)(g*PCH + ch)*FD + f];
  v /= c;
  if (isf32) ((float*)out)[t] = v;
  else       ((ushort16*)out)[t] = f2bf(v);
}

// ---------------- launch ----------------

extern "C" void kernel_launch(void* const* d_in, const int* in_sizes, int n_in,
                              void* d_out, int out_size, void* d_ws, size_t ws_size,
                              hipStream_t stream)
{
  const void* x   = d_in[0];
  const void* ei  = d_in[1];
  const void* bat = d_in[2];
  const void* wl1 = d_in[3];
  const void* bl1 = d_in[4];
  const void* wr1 = d_in[5];
  const void* g1  = d_in[6];
  const void* be1 = d_in[7];
  const void* wl2 = d_in[8];
  const void* bl2 = d_in[9];
  const void* wr2 = d_in[10];
  const void* g2  = d_in[11];
  const void* be2 = d_in[12];
  char* ws = (char*)d_ws;

  // persistent
  uint32* flags   = (uint32*)(ws + 0);            // 2 u32
  uint32* gstart  = (uint32*)(ws + 64);           // 65 u32
  uint32* bbase   = (uint32*)(ws + 384);          // 197 u32
  float*  bnpart  = (float*) (ws + 1280);         // 391*256 f32 -> 401,664
  float*  scale1  = (float*) (ws + 401664);
  float*  shift1  = (float*) (ws + 402176);
  float*  scale2  = (float*) (ws + 402688);
  float*  shift2  = (float*) (ws + 403200);
  uint32* rowstart= (uint32*)(ws + 403712);       // -> 603,712
  uint32* deg     = (uint32*)(ws + 603712);       // -> 803,712
  ushort16* colidx= (ushort16*)(ws + 803712);     // u16 -> 2,403,712
  short*  wfrag   = (short*) (ws + 2403712);      // 2 x 32768 shorts -> 2,534,784
  ushort16* xb    = (ushort16*)(ws + 2534784);    // 12.8 MB -> 15,334,784
  ushort16* aggb  = (ushort16*)(ws + 15334784);   // 12.8 MB -> 28,134,784
  ushort16* hp1   = (ushort16*)(ws + 28134784);   // 12.8 MB -> 40,934,784
  ushort16* hp2   = (ushort16*)(ws + 40934784);   // 12.8 MB -> 53,734,784
  float*  ppart   = (float*) (ws + 53734784);     // 2048*128 f32 -> 54,783,360
  // transient (inside hp1/hp2 region, dead until gemm1 runs):
  uint32* pack0   = (uint32*)(ws + 28134784);     // 3.2 MB
  uint32* pack1   = (uint32*)(ws + 31334784);     // 3.2 MB
  uint32* hist    = (uint32*)(ws + 34534784);     // 391*256 u32
  uint32* off     = (uint32*)(ws + 34935168);     // 391*256 u32

  detect_kernel    <<<1,   64,  0, stream>>>((const uint32*)x, (const uint32*)ei, flags);

  // CSR build (no global atomics)
  pack_hist_kernel <<<GB,  256, 0, stream>>>(ei, flags, pack0, hist);
  scan_hist_kernel <<<1,   256, 0, stream>>>(hist, off, bbase);
  scatter_kernel   <<<GB,  256, 0, stream>>>(pack0, off, pack1);
  bucket_csr_kernel<<<NBK, 256, 0, stream>>>(pack1, bbase, rowstart, deg, colidx);
  gseg_kernel      <<<196, 256, 0, stream>>>(bat, flags, gstart);

  // prep
  xcvt_kernel      <<<3125, 256, 0, stream>>>(x, flags, xb);
  wprep_kernel     <<<256,  256, 0, stream>>>(wl1, wr1, wl2, wr2, flags, wfrag);

  // layer 1
  agg_kernel<0>    <<<3125, 256, 0, stream>>>(xb, rowstart, deg, colidx, nullptr, nullptr, aggb);
  gemm_bn_kernel<0><<<GB,   256, 0, stream>>>(aggb, xb, wfrag, bl1, flags, nullptr, nullptr, hp1, bnpart);
  bn_final_kernel  <<<1,   1024, 0, stream>>>(bnpart, g1, be1, flags, scale1, shift1);

  // layer 2 (BN1+ReLU fused into agg and into gemm's A1 operand)
  agg_kernel<1>    <<<3125, 256, 0, stream>>>(hp1, rowstart, deg, colidx, scale1, shift1, aggb);
  gemm_bn_kernel<1><<<GB,   256, 0, stream>>>(aggb, hp1, wfrag + 32768, bl2, flags, scale1, shift1, hp2, bnpart);
  bn_final_kernel  <<<1,   1024, 0, stream>>>(bnpart, g2, be2, flags, scale2, shift2);

  // pool (BN2 + ReLU fused)
  pool_partial_kernel<<<NGRAPH*PCH, 256, 0, stream>>>(hp2, scale2, shift2, gstart, ppart);
  pool_final_kernel  <<<32,  256, 0, stream>>>(ppart, gstart, d_out, flags);
}

// Round 7
// 300.258 us; speedup vs baseline: 2.4934x; 1.0823x over previous
//
#include <hip/hip_runtime.h>
#include <hip/hip_bf16.h>
#include <stdint.h>

typedef unsigned int uint32;
typedef unsigned short ushort16;

typedef __attribute__((ext_vector_type(8))) short short8;
typedef __attribute__((ext_vector_type(4))) float f32x4;

#define N_NODES 50000
#define N_EDGES 800000
#define FD      128
#define NGRAPH  64
#define MTILES  3125   // N_NODES / 16 exactly
#define NBK     196    // coarse buckets = ceil(50000/256)
#define GB      391    // gemm blocks / sort blocks (2048 edges each)
#define PCH     32     // pool chunks per graph
#define KCH     98     // scan_hist k-chunk = ceil(391/4)

__device__ __forceinline__ float bf2f(ushort16 u){
  union { uint32 i; float f; } v; v.i = ((uint32)u) << 16; return v.f;
}
__device__ __forceinline__ float bf2f_lo(uint32 w){ union{uint32 i;float f;}v; v.i = w << 16; return v.f; }
__device__ __forceinline__ float bf2f_hi(uint32 w){ union{uint32 i;float f;}v; v.i = w & 0xffff0000u; return v.f; }
__device__ __forceinline__ ushort16 f2bf(float f){
  uint32 u = __float_as_uint(f);
  u += 0x7fffu + ((u >> 16) & 1u);   // round-to-nearest-even
  return (ushort16)(u >> 16);
}

// flags[0] = 1 iff float inputs are f32 (else bf16); flags[1] = 1 iff indices are int64
__device__ __forceinline__ int ld_idx(const void* p, uint32 is64, size_t i){
  return is64 ? (int)((const long long*)p)[i] : ((const int*)p)[i];
}
__device__ __forceinline__ float ld_f(const void* p, uint32 isf32, int i){
  return isf32 ? ((const float*)p)[i] : bf2f(((const ushort16*)p)[i]);
}

// ---------------- dtype detection (device-side, 1 wave) ----------------

__global__ void detect_kernel(const uint32* __restrict__ xw, const uint32* __restrict__ eiw,
                              uint32* __restrict__ flags)
{
  int t = threadIdx.x;                       // 64 lanes
  uint32 w = xw[t];
  uint32 e8 = (w >> 7) & 0xFFu;              // exponent field of the LOW bf16 half
  bool bf_like = (e8 >= 0x70u && e8 <= 0x82u);
  unsigned long long m = __ballot(bf_like);
  uint32 hi = (t < 8) ? eiw[2*t + 1] : 1u;
  unsigned long long z = __ballot(hi == 0u);
  if (t == 0){
    flags[0] = (__popcll(m) < 32) ? 1u : 0u;          // isf32
    flags[1] = ((z & 0xFFull) == 0xFFull) ? 1u : 0u;  // is64
  }
}

// ---------------- CSR build: atomic-free 2-level bucket sort ----------------
// blocks [0,GB): pack edges + per-block LDS hist.  blocks [GB, GB+196): gseg.

__global__ __launch_bounds__(256) void pack_gseg_kernel(const void* __restrict__ ei,
    const void* __restrict__ batch, const uint32* __restrict__ flags,
    uint32* __restrict__ pack0, uint32* __restrict__ hist, uint32* __restrict__ gstart)
{
  uint32 is64 = flags[1];
  int tid = threadIdx.x;
  if (blockIdx.x < GB){
    __shared__ uint32 h[256];
    h[tid] = 0u;
    __syncthreads();
    int base = blockIdx.x*2048;
    for (int r = 0; r < 8; ++r){
      int i = base + r*256 + tid;
      if (i < N_EDGES){
        uint32 s = (uint32)ld_idx(ei, is64, i);
        uint32 d = (uint32)ld_idx(ei, is64, (size_t)N_EDGES + i);
        pack0[i] = (d << 16) | s;
        atomicAdd(&h[d >> 8], 1u);             // LDS atomic
      }
    }
    __syncthreads();
    hist[blockIdx.x*256 + tid] = h[tid];
  } else {
    int t = (blockIdx.x - GB)*256 + tid;
    if (t >= N_NODES) return;
    int b1 = ld_idx(batch, is64, t);
    int b0 = (t == 0) ? -1 : ld_idx(batch, is64, t - 1);
    for (int g = b0 + 1; g <= b1; ++g) gstart[g] = (uint32)t;
    if (t == N_NODES - 1)
      for (int g = b1 + 1; g <= NGRAPH; ++g) gstart[g] = (uint32)N_NODES;
  }
}

// 1024 threads: seg=tid>>8 handles k in [seg*KCH, ...): 98 serial iters not 391.
__global__ __launch_bounds__(1024) void scan_hist_kernel(const uint32* __restrict__ hist,
    uint32* __restrict__ off, uint32* __restrict__ bbase)
{
  __shared__ uint32 part[4][256];
  __shared__ uint32 lds[256];
  __shared__ uint32 bb[256];
  int tid = threadIdx.x;
  int seg = tid >> 8, b = tid & 255;
  int k0 = seg*KCH, k1 = (k0 + KCH < GB) ? k0 + KCH : GB;
  uint32 sum = 0;
  for (int k = k0; k < k1; ++k) sum += hist[k*256 + b];
  part[seg][b] = sum;
  __syncthreads();
  uint32 tot = 0, x = 0;
  if (seg == 0){
    tot = part[0][b] + part[1][b] + part[2][b] + part[3][b];
    x = tot; lds[b] = x;
  }
  __syncthreads();
  for (int o = 1; o < 256; o <<= 1){
    uint32 y = 0;
    if (seg == 0 && b >= o) y = lds[b - o];
    __syncthreads();
    if (seg == 0){ x += y; lds[b] = x; }
    __syncthreads();
  }
  if (seg == 0){
    uint32 base = x - tot;                     // exclusive bucket base
    bb[b] = base;
    if (b <= NBK) bbase[b] = (b < NBK) ? base : (uint32)N_EDGES;
  }
  __syncthreads();
  uint32 run = bb[b];
  for (int s = 0; s < seg; ++s) run += part[s][b];
  for (int k = k0; k < k1; ++k){
    off[k*256 + b] = run;
    run += hist[k*256 + b];
  }
}

__global__ __launch_bounds__(256) void scatter_kernel(const uint32* __restrict__ pack0,
    const uint32* __restrict__ off, uint32* __restrict__ pack1)
{
  __shared__ uint32 cur[256];
  int tid = threadIdx.x;
  cur[tid] = off[blockIdx.x*256 + tid];
  __syncthreads();
  int base = blockIdx.x*2048;
  for (int r = 0; r < 8; ++r){
    int i = base + r*256 + tid;
    if (i < N_EDGES){
      uint32 p = pack0[i];
      uint32 pos = atomicAdd(&cur[p >> 24], 1u);   // LDS atomic
      pack1[pos] = p;
    }
  }
}

__global__ __launch_bounds__(256) void bucket_csr_kernel(const uint32* __restrict__ pack1,
    const uint32* __restrict__ bbase, uint32* __restrict__ rowstart,
    uint32* __restrict__ deg, ushort16* __restrict__ colidx)
{
  __shared__ uint32 cnt[256];
  __shared__ uint32 lds[256];
  __shared__ uint32 cur[256];
  int tid = threadIdx.x;
  int bk = blockIdx.x;
  uint32 e0 = bbase[bk], e1 = bbase[bk + 1];
  cnt[tid] = 0u;
  __syncthreads();
  for (uint32 i = e0 + tid; i < e1; i += 256)
    atomicAdd(&cnt[(pack1[i] >> 16) & 255u], 1u);  // LDS atomic
  __syncthreads();
  uint32 v = cnt[tid];
  uint32 x = v;
  lds[tid] = x; __syncthreads();
  for (int o = 1; o < 256; o <<= 1){
    uint32 y = (tid >= o) ? lds[tid - o] : 0u;
    __syncthreads();
    x += y; lds[tid] = x;
    __syncthreads();
  }
  uint32 start = e0 + x - v;
  int node = bk*256 + tid;
  if (node < N_NODES){ rowstart[node] = start; deg[node] = v; }
  cur[tid] = start;
  __syncthreads();
  for (uint32 i = e0 + tid; i < e1; i += 256){
    uint32 p = pack1[i];
    uint32 pos = atomicAdd(&cur[(p >> 16) & 255u], 1u);  // LDS atomic
    colidx[pos] = (ushort16)(p & 0xFFFFu);
  }
}

// ---------------- prep: x->bf16 (f32 only) + W fragment layout --------------
// blocks [0,3125): xcvt (no-op when input already bf16); [3125,3381): wprep.

__global__ __launch_bounds__(256) void prep_kernel(const void* __restrict__ X,
    const void* __restrict__ WL1, const void* __restrict__ WR1,
    const void* __restrict__ WL2, const void* __restrict__ WR2,
    const uint32* __restrict__ flags, ushort16* __restrict__ xb, short* __restrict__ wfrag)
{
  uint32 isf32 = flags[0];
  if (blockIdx.x < 3125){
    if (!isf32) return;                        // bf16 input used in place
    size_t e = ((size_t)blockIdx.x*256 + threadIdx.x)*8;
    const float* p = (const float*)X + e;
    float4 u = *(const float4*)p;
    float4 v = *(const float4*)(p + 4);
    uint4 o;
    o.x = (uint32)f2bf(u.x) | ((uint32)f2bf(u.y) << 16);
    o.y = (uint32)f2bf(u.z) | ((uint32)f2bf(u.w) << 16);
    o.z = (uint32)f2bf(v.x) | ((uint32)f2bf(v.y) << 16);
    o.w = (uint32)f2bf(v.z) | ((uint32)f2bf(v.w) << 16);
    *(uint4*)(xb + e) = o;
  } else {
    int t = (blockIdx.x - 3125)*256 + threadIdx.x;   // 65536 total
    int layer = t >> 15;
    int r = t & 32767;
    int k = r >> 7, n = r & 127;
    const void* w = layer ? (k < 128 ? WL2 : WR2) : (k < 128 ? WL1 : WR1);
    int kk = k & 127;
    float wv = ld_f(w, isf32, kk*128 + n);
    int off = (((k >> 5)*8 + (n >> 4))*64 + (n & 15) + 16*((kk >> 3) & 3))*8 + (kk & 7);
    wfrag[layer*32768 + off] = (short)f2bf(wv);
  }
}

// ---------------- mean aggregation (pull, CSR); APPLY fuses BN+ReLU --------
// Unroll-by-4: 4 independent 16B gathers in flight per thread (latency hiding).

__device__ __forceinline__ void acc8(float* a, uint4 v, const float* s0, const float* h0, int APPLY){
  float f[8];
  f[0] = bf2f_lo(v.x); f[1] = bf2f_hi(v.x);
  f[2] = bf2f_lo(v.y); f[3] = bf2f_hi(v.y);
  f[4] = bf2f_lo(v.z); f[5] = bf2f_hi(v.z);
  f[6] = bf2f_lo(v.w); f[7] = bf2f_hi(v.w);
#pragma unroll
  for (int j = 0; j < 8; ++j)
    a[j] += APPLY ? fmaxf(f[j]*s0[j] + h0[j], 0.f) : f[j];
}

template<int APPLY>
__global__ __launch_bounds__(256) void agg_kernel(const ushort16* __restrict__ Xd,
    const void* __restrict__ Xraw,
    const uint32* __restrict__ rowstart, const uint32* __restrict__ deg,
    const ushort16* __restrict__ colidx,
    const float* __restrict__ sc, const float* __restrict__ sh,
    ushort16* __restrict__ out, const uint32* __restrict__ flags)
{
  const ushort16* X = (Xraw && !flags[0]) ? (const ushort16*)Xraw : Xd;
  int t = blockIdx.x*256 + threadIdx.x;
  int node = t >> 4;
  int l = t & 15;
  if (node >= N_NODES) return;
  uint32 st = rowstart[node];
  uint32 d  = deg[node];
  float s0[8], h0[8];
#pragma unroll
  for (int j = 0; j < 8; ++j){
    s0[j] = APPLY ? sc[l*8 + j] : 0.f;
    h0[j] = APPLY ? sh[l*8 + j] : 0.f;
  }
  float a[8];
#pragma unroll
  for (int j = 0; j < 8; ++j) a[j] = 0.f;
  uint32 i = 0;
  for (; i + 4 <= d; i += 4){
    uint32 c0 = colidx[st + i + 0];
    uint32 c1 = colidx[st + i + 1];
    uint32 c2 = colidx[st + i + 2];
    uint32 c3 = colidx[st + i + 3];
    uint4 v0 = *(const uint4*)(X + (size_t)c0*FD + l*8);
    uint4 v1 = *(const uint4*)(X + (size_t)c1*FD + l*8);
    uint4 v2 = *(const uint4*)(X + (size_t)c2*FD + l*8);
    uint4 v3 = *(const uint4*)(X + (size_t)c3*FD + l*8);
    acc8(a, v0, s0, h0, APPLY);
    acc8(a, v1, s0, h0, APPLY);
    acc8(a, v2, s0, h0, APPLY);
    acc8(a, v3, s0, h0, APPLY);
  }
  for (; i < d; ++i){
    uint32 c = colidx[st + i];
    uint4 v = *(const uint4*)(X + (size_t)c*FD + l*8);
    acc8(a, v, s0, h0, APPLY);
  }
  float inv = 1.f / fmaxf((float)d, 1.f);
  uint4 o;
  o.x = (uint32)f2bf(a[0]*inv) | ((uint32)f2bf(a[1]*inv) << 16);
  o.y = (uint32)f2bf(a[2]*inv) | ((uint32)f2bf(a[3]*inv) << 16);
  o.z = (uint32)f2bf(a[4]*inv) | ((uint32)f2bf(a[5]*inv) << 16);
  o.w = (uint32)f2bf(a[6]*inv) | ((uint32)f2bf(a[7]*inv) << 16);
  *(uint4*)(out + (size_t)node*FD + l*8) = o;
}

// ---------------- fused GEMM + bias + BN-stat partials ----------------------

__device__ __forceinline__ short8 affine_relu8(short8 a, const float* sc, const float* sh, int koff){
  short8 r;
#pragma unroll
  for (int j = 0; j < 8; ++j){
    float v = bf2f((ushort16)a[j]) * sc[koff + j] + sh[koff + j];
    r[j] = (short)f2bf(fmaxf(v, 0.f));
  }
  return r;
}

template<int APPLY>
__global__ __launch_bounds__(256) void gemm_bn_kernel(
    const ushort16* __restrict__ A0, const ushort16* __restrict__ A1d,
    const void* __restrict__ A1raw,
    const short* __restrict__ wfrag, const void* __restrict__ bias,
    const uint32* __restrict__ flags,
    const float* __restrict__ sc, const float* __restrict__ sh,
    ushort16* __restrict__ hpre, float* __restrict__ bnpart)
{
  __shared__ float red[256];
  uint32 isf32 = flags[0];
  const ushort16* A1 = (A1raw && !isf32) ? (const ushort16*)A1raw : A1d;
  int tid = threadIdx.x;
  red[tid] = 0.f;
  int wave = tid >> 6, lane = tid & 63, lq = lane >> 4, lm = lane & 15;
  int mt0 = blockIdx.x*8 + wave*2;
  int mt1 = mt0 + 1;
  bool v0 = mt0 < MTILES, v1 = mt1 < MTILES;
  f32x4 acc0[8], acc1[8];
#pragma unroll
  for (int i = 0; i < 8; ++i){ acc0[i] = (f32x4){0.f,0.f,0.f,0.f}; acc1[i] = (f32x4){0.f,0.f,0.f,0.f}; }
  size_t m0 = (size_t)((v0 ? mt0 : 0)*16 + lm);
  size_t m1 = (size_t)((v1 ? mt1 : 0)*16 + lm);

#pragma unroll
  for (int ks = 0; ks < 8; ++ks){
    int koff = (ks & 3)*32 + lq*8;
    const short* srcp = (const short*)(ks < 4 ? A0 : A1);
    short8 a0 = *(const short8*)(srcp + m0*FD + koff);
    short8 a1 = *(const short8*)(srcp + m1*FD + koff);
    if (APPLY && ks >= 4){
      a0 = affine_relu8(a0, sc, sh, koff);
      a1 = affine_relu8(a1, sc, sh, koff);
    }
#pragma unroll
    for (int nt = 0; nt < 8; ++nt){
      short8 b = *(const short8*)&wfrag[((ks*8 + nt)*64 + lane)*8];
      acc0[nt] = __builtin_amdgcn_mfma_f32_16x16x32_bf16(a0, b, acc0[nt], 0, 0, 0);
      acc1[nt] = __builtin_amdgcn_mfma_f32_16x16x32_bf16(a1, b, acc1[nt], 0, 0, 0);
    }
  }

  __syncthreads();                              // red[] zero-init visible to all
#pragma unroll
  for (int nt = 0; nt < 8; ++nt){
    int colc = nt*16 + lm;                      // C/D: col = lane&15
    float bb = ld_f(bias, isf32, colc);
    float s = 0.f, s2 = 0.f;
    if (v0){
      size_t nb = (size_t)(mt0*16 + lq*4);      // C/D: row = quad*4 + reg
#pragma unroll
      for (int r = 0; r < 4; ++r){
        float val = acc0[nt][r] + bb;
        hpre[(nb + r)*FD + colc] = f2bf(val);
        s += val; s2 += val*val;
      }
    }
    if (v1){
      size_t nb = (size_t)(mt1*16 + lq*4);
#pragma unroll
      for (int r = 0; r < 4; ++r){
        float val = acc1[nt][r] + bb;
        hpre[(nb + r)*FD + colc] = f2bf(val);
        s += val; s2 += val*val;
      }
    }
    s  += __shfl_xor(s, 16);  s  += __shfl_xor(s, 32);
    s2 += __shfl_xor(s2, 16); s2 += __shfl_xor(s2, 32);
    if (lq == 0){
      atomicAdd(&red[colc], s);                 // LDS atomic
      atomicAdd(&red[128 + colc], s2);
    }
  }
  __syncthreads();
  bnpart[blockIdx.x*256 + tid] = red[tid];
}

// ---------------- BN finalize (partials reduce) -----------------------------

__global__ __launch_bounds__(1024) void bn_final_kernel(const float* __restrict__ bnpart,
    const void* __restrict__ gamma, const void* __restrict__ beta,
    const uint32* __restrict__ flags, float* __restrict__ scale, float* __restrict__ shift)
{
  __shared__ float ls[1024], lq2[1024];
  uint32 isf32 = flags[0];
  int tid = threadIdx.x, f = tid & 127, seg = tid >> 7;
  float s = 0.f, q = 0.f;
  for (int b = seg; b < GB; b += 8){
    s += bnpart[b*256 + f];
    q += bnpart[b*256 + 128 + f];
  }
  ls[tid] = s; lq2[tid] = q;
  __syncthreads();
  if (tid < 128){
#pragma unroll
    for (int k = 1; k < 8; ++k){ s += ls[k*128 + f]; q += lq2[k*128 + f]; }
    const float invN = 1.0f / (float)N_NODES;
    float mu  = s * invN;
    float var = q * invN - mu*mu;
    float scv = ld_f(gamma, isf32, f) * rsqrtf(var + 1e-5f);
    scale[f] = scv;
    shift[f] = ld_f(beta, isf32, f) - mu * scv;
  }
}

// ---------------- pool (BN2 + ReLU fused), high-occupancy -------------------

__global__ __launch_bounds__(256) void pool_partial_kernel(const ushort16* __restrict__ hp,
    const float* __restrict__ scale, const float* __restrict__ shift,
    const uint32* __restrict__ gstart, float* __restrict__ pool_part)
{
  __shared__ float wred[4*16*8];                 // 2 KB
  int tid = threadIdx.x;
  int g = blockIdx.x >> 5, chunk = blockIdx.x & 31;
  int slot = tid >> 4, l = tid & 15;
  int wave = tid >> 6, lane = tid & 63;
  uint32 st = gstart[g], cnt = gstart[g+1] - st;
  uint32 per = (cnt + PCH - 1) >> 5;
  uint32 b0 = st + chunk*per;
  uint32 b1 = b0 + per;
  uint32 e1 = st + cnt;
  if (b1 > e1) b1 = e1;
  float s0[8], h0[8], a[8];
#pragma unroll
  for (int j = 0; j < 8; ++j){ s0[j] = scale[l*8 + j]; h0[j] = shift[l*8 + j]; a[j] = 0.f; }
  for (uint32 n = b0 + slot; n < b1; n += 16){
    const uint4 v = *(const uint4*)(hp + (size_t)n*FD + l*8);
    float f[8];
    f[0] = bf2f_lo(v.x); f[1] = bf2f_hi(v.x);
    f[2] = bf2f_lo(v.y); f[3] = bf2f_hi(v.y);
    f[4] = bf2f_lo(v.z); f[5] = bf2f_hi(v.z);
    f[6] = bf2f_lo(v.w); f[7] = bf2f_hi(v.w);
#pragma unroll
    for (int j = 0; j < 8; ++j) a[j] += fmaxf(f[j]*s0[j] + h0[j], 0.f);
  }
#pragma unroll
  for (int j = 0; j < 8; ++j){
    a[j] += __shfl_xor(a[j], 16);
    a[j] += __shfl_xor(a[j], 32);
  }
  if (lane < 16){
#pragma unroll
    for (int j = 0; j < 8; ++j) wred[(wave*16 + lane)*8 + j] = a[j];
  }
  __syncthreads();
  if (tid < 16){
    float r[8];
#pragma unroll
    for (int j = 0; j < 8; ++j)
      r[j] = wred[(0*16 + tid)*8 + j] + wred[(1*16 + tid)*8 + j]
           + wred[(2*16 + tid)*8 + j] + wred[(3*16 + tid)*8 + j];
    float* dst = pool_part + (size_t)blockIdx.x*FD + tid*8;
#pragma unroll
    for (int j = 0; j < 8; ++j) dst[j] = r[j];
  }
}

__global__ void pool_final_kernel(const float* __restrict__ pool_part,
    const uint32* __restrict__ gstart, void* __restrict__ out, const uint32* __restrict__ flags)
{
  uint32 isf32 = flags[0];
  int t = blockIdx.x*256 + threadIdx.x;          // t < 8192
  int g = t >> 7, f = t & 127;
  float c = fmaxf((float)(gstart[g+1] - gstart[g]), 1.f);
  float v = 0.f;
#pragma unroll 8
  for (int ch = 0; ch < PCH; ++ch)
    v += pool_part[(size_t)(g*PCH + ch)*FD + f];
  v /= c;
  if (isf32) ((float*)out)[t] = v;
  else       ((ushort16*)out)[t] = f2bf(v);
}

// ---------------- launch ----------------

extern "C" void kernel_launch(void* const* d_in, const int* in_sizes, int n_in,
                              void* d_out, int out_size, void* d_ws, size_t ws_size,
                              hipStream_t stream)
{
  const void* x   = d_in[0];
  const void* ei  = d_in[1];
  const void* bat = d_in[2];
  const void* wl1 = d_in[3];
  const void* bl1 = d_in[4];
  const void* wr1 = d_in[5];
  const void* g1  = d_in[6];
  const void* be1 = d_in[7];
  const void* wl2 = d_in[8];
  const void* bl2 = d_in[9];
  const void* wr2 = d_in[10];
  const void* g2  = d_in[11];
  const void* be2 = d_in[12];
  char* ws = (char*)d_ws;

  // persistent
  uint32* flags   = (uint32*)(ws + 0);            // 2 u32
  uint32* gstart  = (uint32*)(ws + 64);           // 65 u32
  uint32* bbase   = (uint32*)(ws + 384);          // 197 u32
  float*  bnpart  = (float*) (ws + 1280);         // 391*256 f32 -> 401,664
  float*  scale1  = (float*) (ws + 401664);
  float*  shift1  = (float*) (ws + 402176);
  float*  scale2  = (float*) (ws + 402688);
  float*  shift2  = (float*) (ws + 403200);
  uint32* rowstart= (uint32*)(ws + 403712);       // -> 603,712
  uint32* deg     = (uint32*)(ws + 603712);       // -> 803,712
  ushort16* colidx= (ushort16*)(ws + 803712);     // u16 -> 2,403,712
  short*  wfrag   = (short*) (ws + 2403712);      // 2 x 32768 shorts -> 2,534,784
  ushort16* xb    = (ushort16*)(ws + 2534784);    // 12.8 MB -> 15,334,784
  ushort16* aggb  = (ushort16*)(ws + 15334784);   // 12.8 MB -> 28,134,784
  ushort16* hp1   = (ushort16*)(ws + 28134784);   // 12.8 MB -> 40,934,784
  ushort16* hp2   = (ushort16*)(ws + 40934784);   // 12.8 MB -> 53,734,784
  float*  ppart   = (float*) (ws + 53734784);     // 2048*128 f32 -> 54,783,360
  // transient (inside hp1/hp2 region, dead until gemm1 runs):
  uint32* pack0   = (uint32*)(ws + 28134784);     // 3.2 MB
  uint32* pack1   = (uint32*)(ws + 31334784);     // 3.2 MB
  uint32* hist    = (uint32*)(ws + 34534784);     // 391*256 u32
  uint32* off     = (uint32*)(ws + 34935168);     // 391*256 u32

  detect_kernel    <<<1,   64,  0, stream>>>((const uint32*)x, (const uint32*)ei, flags);

  // CSR build (no global atomics) + graph segments
  pack_gseg_kernel <<<GB + 196, 256, 0, stream>>>(ei, bat, flags, pack0, hist, gstart);
  scan_hist_kernel <<<1,  1024, 0, stream>>>(hist, off, bbase);
  scatter_kernel   <<<GB,  256, 0, stream>>>(pack0, off, pack1);
  bucket_csr_kernel<<<NBK, 256, 0, stream>>>(pack1, bbase, rowstart, deg, colidx);

  // prep (xcvt no-ops when input is bf16; wprep always)
  prep_kernel      <<<3381, 256, 0, stream>>>(x, wl1, wr1, wl2, wr2, flags, xb, wfrag);

  // layer 1 (reads x directly when bf16)
  agg_kernel<0>    <<<3125, 256, 0, stream>>>(xb, x, rowstart, deg, colidx, nullptr, nullptr, aggb, flags);
  gemm_bn_kernel<0><<<GB,   256, 0, stream>>>(aggb, xb, x, wfrag, bl1, flags, nullptr, nullptr, hp1, bnpart);
  bn_final_kernel  <<<1,   1024, 0, stream>>>(bnpart, g1, be1, flags, scale1, shift1);

  // layer 2 (BN1+ReLU fused into agg and into gemm's A1 operand)
  agg_kernel<1>    <<<3125, 256, 0, stream>>>(hp1, nullptr, rowstart, deg, colidx, scale1, shift1, aggb, flags);
  gemm_bn_kernel<1><<<GB,   256, 0, stream>>>(aggb, hp1, nullptr, wfrag + 32768, bl2, flags, scale1, shift1, hp2, bnpart);
  bn_final_kernel  <<<1,   1024, 0, stream>>>(bnpart, g2, be2, flags, scale2, shift2);

  // pool (BN2 + ReLU fused)
  pool_partial_kernel<<<NGRAPH*PCH, 256, 0, stream>>>(hp2, scale2, shift2, gstart, ppart);
  pool_final_kernel  <<<32,  256, 0, stream>>>(ppart, gstart, d_out, flags);
}